// Round 2
// 688.959 us; speedup vs baseline: 1.0824x; 1.0824x over previous
//
#include <hip/hip_runtime.h>
#include <hip/hip_bf16.h>

// GCN (3-layer, JK=sum) on MI355X.
// R8b: resubmit of R8 (container failed; audit found one latent OOB-pattern
//     write in k_cnt for t>=NBK spilling past cntT — now guarded).
// R8: CSR build rework. Old k_bin spent ~118us/iter on 1024-way contended
//     returning atomics + 81MB write-amplified 4B scatters. Replaced by
//     deterministic 2-pass LDS radix partition by dst>>9 (196 buckets x 512
//     rows): k_cnt (LDS histogram -> transposed count table, no global
//     atomics), k_colscan + k_bktscan (exact scans -> per (block,bucket)
//     bases), k_part2 (LDS counting sort, coalesced ebuf writes), k_csr2
//     (per-bucket CSR finish fully in LDS, coalesced rowptr/col/dinv writes).
// R7: GEMM via v_mfma_f32_16x16x32_bf16 (unchanged here).

constexpr int NN = 100000;
constexpr int EE = 1600000;
constexpr int DD = 128;
constexpr float BN_EPS = 1e-5f;
constexpr int NPAD = 100096;
constexpr int SPMM_GRID = NN / 16;              // 6250
constexpr int GEMM_GRID = (NN + 63) / 64;       // 1563

// radix partition params
constexpr int NBK = (NN + 511) / 512;           // 196 coarse buckets (dst>>9)
constexpr int PB = 4096;                        // edges per partition block
constexpr int PART_GRID = (EE + PB - 1) / PB;   // 391
constexpr int CSTRIDE = 400;                    // >= PART_GRID, count-table stride
constexpr int CAPL = 10240;                     // LDS colseg capacity (mean 8192 + ~22 sigma)

typedef __attribute__((ext_vector_type(8))) short bf16x8;
typedef __attribute__((ext_vector_type(4))) float f32x4;

__device__ __forceinline__ float bfhi(unsigned int u) {
  union { unsigned int i; float f; } v; v.i = u & 0xffff0000u; return v.f;
}
__device__ __forceinline__ float bflo(unsigned int u) {
  union { unsigned int i; float f; } v; v.i = u << 16; return v.f;
}
__device__ __forceinline__ unsigned short f2bf(float f) {
  union { float f; unsigned int i; } v;
  v.f = f;
  unsigned int r = v.i + 0x7FFFu + ((v.i >> 16) & 1u);   // RNE
  return (unsigned short)(r >> 16);
}
__device__ __forceinline__ void acc8(uint4 u, float4& a0, float4& a1) {
  a0.x += bflo(u.x); a0.y += bfhi(u.x);
  a0.z += bflo(u.y); a0.w += bfhi(u.y);
  a1.x += bflo(u.z); a1.y += bfhi(u.z);
  a1.z += bflo(u.w); a1.w += bfhi(u.w);
}
__device__ __forceinline__ int wave_incl_scan(int v, int lane) {
#pragma unroll
  for (int off = 1; off < 64; off <<= 1) {
    int x = __shfl_up(v, off, 64);
    if (lane >= off) v += x;
  }
  return v;
}

// --- CSR build pass 1: per-(block,bucket) counts, transposed [bkt][blk] ---
__global__ __launch_bounds__(256)
void k_cnt(const int* __restrict__ dst, int* __restrict__ cntT) {
  __shared__ int cnt[256];
  const int t = threadIdx.x;
  const int e0 = blockIdx.x * PB;
  const int nv = min(PB, EE - e0);
  cnt[t] = 0;
  __syncthreads();
  for (int i = t; i < nv; i += 256)
    atomicAdd(&cnt[dst[e0 + i] >> 9], 1);
  __syncthreads();
  if (t < NBK) cntT[t * CSTRIDE + blockIdx.x] = cnt[t];
}

// --- per-bucket column scan over blocks: baseT[bkt][blk] = edges of bkt in
//     blocks < blk; gtot[bkt] = total edges of bkt ---
__global__ __launch_bounds__(64)
void k_colscan(const int* __restrict__ cntT, int* __restrict__ baseT,
               int* __restrict__ gtot) {
  const int b = blockIdx.x;
  const int lane = threadIdx.x;
  int c[7];
  int ls = 0;
#pragma unroll
  for (int j = 0; j < 7; ++j) {
    const int idx = lane * 7 + j;
    c[j] = (idx < PART_GRID) ? cntT[b * CSTRIDE + idx] : 0;
    ls += c[j];
  }
  const int is = wave_incl_scan(ls, lane);
  int run = is - ls;
#pragma unroll
  for (int j = 0; j < 7; ++j) {
    const int idx = lane * 7 + j;
    if (idx < PART_GRID) baseT[b * CSTRIDE + idx] = run;
    run += c[j];
  }
  if (lane == 63) gtot[b] = is;
}

// --- exclusive scan over 196 bucket totals -> bktbase[0..256] ---
__global__ __launch_bounds__(64)
void k_bktscan(const int* __restrict__ gtot, int* __restrict__ bktbase) {
  const int lane = threadIdx.x;
  int c[4];
  int ls = 0;
#pragma unroll
  for (int j = 0; j < 4; ++j) {
    const int idx = lane * 4 + j;
    c[j] = (idx < NBK) ? gtot[idx] : 0;
    ls += c[j];
  }
  const int is = wave_incl_scan(ls, lane);
  int run = is - ls;
#pragma unroll
  for (int j = 0; j < 4; ++j) {
    bktbase[lane * 4 + j] = run;
    run += c[j];
  }
  if (lane == 63) bktbase[256] = is;   // == EE
}

// --- CSR build pass 2: LDS counting sort per block, coalesced ebuf writes.
//     ebuf entry = (src << 9) | (dst & 511), bucket implicit from region. ---
__global__ __launch_bounds__(256)
void k_part2(const int* __restrict__ src, const int* __restrict__ dst,
             const int* __restrict__ baseT, const int* __restrict__ bktbase,
             unsigned* __restrict__ ebuf) {
  __shared__ unsigned sorted[PB];
  __shared__ unsigned char sortedb[PB];
  alignas(16) __shared__ int cnt[256];
  __shared__ int cur[256], start[256], gbase[256];
  const int t = threadIdx.x;
  const int lane = t & 63;
  const int e0 = blockIdx.x * PB;
  const int nv = min(PB, EE - e0);
  cnt[t] = 0;
  if (t < NBK) gbase[t] = bktbase[t] + baseT[t * CSTRIDE + blockIdx.x];
  __syncthreads();
  int es[PB / 256], ed[PB / 256];
#pragma unroll
  for (int j = 0; j < PB / 256; ++j) {
    const int i = t + j * 256;
    if (i < nv) {
      es[j] = src[e0 + i];
      ed[j] = dst[e0 + i];
      atomicAdd(&cnt[ed[j] >> 9], 1);
    } else {
      ed[j] = -1;
    }
  }
  __syncthreads();
  if (t < 64) {
    const int4 c = *(const int4*)&cnt[lane * 4];
    const int ls = c.x + c.y + c.z + c.w;
    const int is = wave_incl_scan(ls, lane);
    int run = is - ls;
    start[lane * 4] = run; cur[lane * 4] = run; run += c.x;
    start[lane * 4 + 1] = run; cur[lane * 4 + 1] = run; run += c.y;
    start[lane * 4 + 2] = run; cur[lane * 4 + 2] = run; run += c.z;
    start[lane * 4 + 3] = run; cur[lane * 4 + 3] = run;
  }
  __syncthreads();
#pragma unroll
  for (int j = 0; j < PB / 256; ++j) {
    if (ed[j] >= 0) {
      const int bkt = ed[j] >> 9;
      const int p = atomicAdd(&cur[bkt], 1);
      sorted[p] = ((unsigned)es[j] << 9) | (unsigned)(ed[j] & 511);
      sortedb[p] = (unsigned char)bkt;
    }
  }
  __syncthreads();
  for (int i = t; i < nv; i += 256) {
    const int bkt = sortedb[i];
    ebuf[(size_t)gbase[bkt] + (i - start[bkt])] = sorted[i];
  }
}

// --- CSR finish: one block per bucket, rows/col fully in LDS, all writes
//     coalesced. ---
__global__ __launch_bounds__(256)
void k_csr2(const unsigned* __restrict__ ebuf, const int* __restrict__ bktbase,
            int* __restrict__ rowptr, int* __restrict__ col,
            float* __restrict__ dinv) {
  __shared__ int rowcnt[512], rowbase[512], rowcur[512];
  __shared__ unsigned colseg[CAPL];
  const int b = blockIdx.x;
  const int t = threadIdx.x;
  const int ebase = bktbase[b];
  const int n = min(bktbase[b + 1] - ebase, CAPL);
  const unsigned* eb = &ebuf[ebase];
  rowcnt[t] = 0;
  rowcnt[t + 256] = 0;
  __syncthreads();
  for (int i = t; i < n; i += 256)
    atomicAdd(&rowcnt[eb[i] & 511u], 1);
  __syncthreads();
  if (t < 64) {
    int v[8];
    int ls = 0;
#pragma unroll
    for (int j = 0; j < 8; ++j) { v[j] = rowcnt[t * 8 + j]; ls += v[j]; }
    const int is = wave_incl_scan(ls, t);
    int run = is - ls;
#pragma unroll
    for (int j = 0; j < 8; ++j) {
      rowbase[t * 8 + j] = run;
      rowcur[t * 8 + j] = run;
      run += v[j];
    }
  }
  __syncthreads();
#pragma unroll
  for (int h = 0; h < 2; ++h) {
    const int rl = t + h * 256;
    const int r = b * 512 + rl;
    if (r < NN) {
      rowptr[r] = ebase + rowbase[rl];
      dinv[r] = rsqrtf((float)rowcnt[rl] + 1.0f);
    }
  }
  if (b == NBK - 1 && t == 0) rowptr[NN] = ebase + n;
  for (int i = t; i < n; i += 256) {
    const unsigned u = eb[i];
    const int p = atomicAdd(&rowcur[u & 511u], 1);
    colseg[p] = u >> 9;
  }
  __syncthreads();
  for (int i = t; i < n; i += 256) col[ebase + i] = (int)colseg[i];
}

// --- W transpose+cvt: Wt[l][c][k] = bf16(W[l][k][c]) --- grid = 3 blocks
__global__ __launch_bounds__(256)
void k_wt(const float* __restrict__ W, unsigned short* __restrict__ Wt) {
  const float* Ws = W + (size_t)blockIdx.x * DD * DD;
  unsigned short* Wo = Wt + (size_t)blockIdx.x * DD * DD;
  for (int i = threadIdx.x; i < DD * DD; i += 256) {
    const int k = i >> 7, c = i & 127;
    Wo[c * DD + k] = f2bf(Ws[i]);
  }
}

// --- MFMA GEMM: hsb[r][c] = bf16( dinv[r] * sum_k h[r][k] * W[k][c] ) ---
__global__ __launch_bounds__(256)
void k_gemm(const float* __restrict__ h, const unsigned short* __restrict__ Wt,
            const float* __restrict__ dinv, unsigned short* __restrict__ hsb) {
  const int lane = threadIdx.x & 63;
  const int wave = threadIdx.x >> 6;          // 0..3
  const int n15 = lane & 15;
  const int quad = lane >> 4;                 // 0..3
  const int rbase = blockIdx.x * 64 + wave * 16;
  const int arow = min(rbase + n15, NN - 1);  // A-load row (clamped; stores guarded)

  f32x4 acc[8];
#pragma unroll
  for (int ct = 0; ct < 8; ++ct) acc[ct] = (f32x4){0.f, 0.f, 0.f, 0.f};

#pragma unroll
  for (int kc = 0; kc < 4; ++kc) {
    const int k0 = kc * 32 + quad * 8;
    const float4 a0 = *(const float4*)&h[(size_t)arow * DD + k0];
    const float4 a1 = *(const float4*)&h[(size_t)arow * DD + k0 + 4];
    bf16x8 af;
    af[0] = (short)f2bf(a0.x); af[1] = (short)f2bf(a0.y);
    af[2] = (short)f2bf(a0.z); af[3] = (short)f2bf(a0.w);
    af[4] = (short)f2bf(a1.x); af[5] = (short)f2bf(a1.y);
    af[6] = (short)f2bf(a1.z); af[7] = (short)f2bf(a1.w);
#pragma unroll
    for (int ct = 0; ct < 8; ++ct) {
      const bf16x8 bf = *(const bf16x8*)&Wt[(size_t)(ct * 16 + n15) * DD + k0];
      acc[ct] = __builtin_amdgcn_mfma_f32_16x16x32_bf16(af, bf, acc[ct], 0, 0, 0);
    }
  }

#pragma unroll
  for (int i = 0; i < 4; ++i) {
    const int r = rbase + quad * 4 + i;
    if (r < NN) {
      const float dv = dinv[r];
#pragma unroll
      for (int ct = 0; ct < 8; ++ct)
        hsb[(size_t)r * DD + ct * 16 + n15] = f2bf(acc[ct][i] * dv);
    }
  }
}

// --- SpMM (unchanged) ---
__global__ __launch_bounds__(256)
void k_spmm(const unsigned short* __restrict__ hsb, const int* __restrict__ rowptr,
            const int* __restrict__ col, const float* __restrict__ dinv,
            const float* __restrict__ bias, float* __restrict__ hout,
            float* __restrict__ out, float* __restrict__ partials,
            const int mode) {
  const int lane = threadIdx.x & 15;     // 16 lanes / row
  const int g = threadIdx.x >> 4;        // 0..15 rows / block
  const int c8 = lane * 8;
  const int d = blockIdx.x * 16 + g;
  float4 a0 = make_float4(0.f, 0.f, 0.f, 0.f);
  float4 a1 = make_float4(0.f, 0.f, 0.f, 0.f);
  float4 bs0 = a0, bs1 = a0, q0 = a0, q1 = a0;
  if (d < NN) {
    const unsigned short* rowp = &hsb[(size_t)d * DD + c8];
    acc8(*(const uint4*)rowp, a0, a1);                 // self-loop term
    int j = rowptr[d];
    const int e1 = rowptr[d + 1];
    for (; j + 3 < e1; j += 4) {
      const int s0 = col[j], s1 = col[j + 1], s2 = col[j + 2], s3 = col[j + 3];
      const uint4 u0 = *(const uint4*)&hsb[(size_t)s0 * DD + c8];
      const uint4 u1 = *(const uint4*)&hsb[(size_t)s1 * DD + c8];
      const uint4 u2 = *(const uint4*)&hsb[(size_t)s2 * DD + c8];
      const uint4 u3 = *(const uint4*)&hsb[(size_t)s3 * DD + c8];
      acc8(u0, a0, a1); acc8(u1, a0, a1);
      acc8(u2, a0, a1); acc8(u3, a0, a1);
    }
    for (; j < e1; ++j) {
      const uint4 u0 = *(const uint4*)&hsb[(size_t)col[j] * DD + c8];
      acc8(u0, a0, a1);
    }
    const float dv = dinv[d];
    const float4 b0 = *(const float4*)&bias[c8];
    const float4 b1 = *(const float4*)&bias[c8 + 4];
    float4 o0, o1;
    o0.x = fmaxf(fmaf(a0.x, dv, b0.x), 0.f);
    o0.y = fmaxf(fmaf(a0.y, dv, b0.y), 0.f);
    o0.z = fmaxf(fmaf(a0.z, dv, b0.z), 0.f);
    o0.w = fmaxf(fmaf(a0.w, dv, b0.w), 0.f);
    o1.x = fmaxf(fmaf(a1.x, dv, b1.x), 0.f);
    o1.y = fmaxf(fmaf(a1.y, dv, b1.y), 0.f);
    o1.z = fmaxf(fmaf(a1.z, dv, b1.z), 0.f);
    o1.w = fmaxf(fmaf(a1.w, dv, b1.w), 0.f);
    if (mode == 0) {
      *(float4*)&hout[(size_t)d * DD + c8] = o0;
      *(float4*)&hout[(size_t)d * DD + c8 + 4] = o1;
      bs0 = o0; bs1 = o1;
      q0.x = o0.x * o0.x; q0.y = o0.y * o0.y;
      q0.z = o0.z * o0.z; q0.w = o0.w * o0.w;
      q1.x = o1.x * o1.x; q1.y = o1.y * o1.y;
      q1.z = o1.z * o1.z; q1.w = o1.w * o1.w;
    } else {
      float4 p0 = *(const float4*)&out[(size_t)d * DD + c8];
      float4 p1 = *(const float4*)&out[(size_t)d * DD + c8 + 4];
      p0.x += o0.x; p0.y += o0.y; p0.z += o0.z; p0.w += o0.w;
      p1.x += o1.x; p1.y += o1.y; p1.z += o1.z; p1.w += o1.w;
      *(float4*)&out[(size_t)d * DD + c8] = p0;
      *(float4*)&out[(size_t)d * DD + c8 + 4] = p1;
    }
  }
  if (mode == 0) {
    __shared__ float red[256 * 16];
    float* my = &red[threadIdx.x * 16];
    my[0] = bs0.x; my[1] = bs0.y; my[2] = bs0.z; my[3] = bs0.w;
    my[4] = bs1.x; my[5] = bs1.y; my[6] = bs1.z; my[7] = bs1.w;
    my[8] = q0.x;  my[9] = q0.y;  my[10] = q0.z; my[11] = q0.w;
    my[12] = q1.x; my[13] = q1.y; my[14] = q1.z; my[15] = q1.w;
    __syncthreads();
    const int t = threadIdx.x;
    float s = 0.f;
#pragma unroll
    for (int gg = 0; gg < 16; ++gg) s += red[gg * 256 + t];
    partials[(size_t)t * SPMM_GRID + blockIdx.x] = s;
  }
}

__global__ __launch_bounds__(256)
void k_bnred(const float* __restrict__ partials, float* __restrict__ stat) {
  __shared__ float s[256];
  const int slot = blockIdx.x;
  float v = 0.f;
  for (int i = threadIdx.x; i < SPMM_GRID; i += 256)
    v += partials[(size_t)slot * SPMM_GRID + i];
  s[threadIdx.x] = v;
  __syncthreads();
  for (int off = 128; off; off >>= 1) {
    if (threadIdx.x < off) s[threadIdx.x] += s[threadIdx.x + off];
    __syncthreads();
  }
  if (threadIdx.x == 0) stat[slot] = s[0];
}

__global__ __launch_bounds__(256)
void k_bnfin(const float* __restrict__ stat, float* __restrict__ ss,
             const float* __restrict__ gamma, const float* __restrict__ beta) {
  __shared__ float tot[256];            // [kind*128 + c]
  const int t = threadIdx.x;
  const float s = stat[t];
  const int lane16 = t >> 4, q = t & 15;
  const int c = lane16 * 8 + (q & 7), kind = q >> 3;
  tot[kind * 128 + c] = s;
  __syncthreads();
  if (t < 128) {
    const float m = tot[t] * (1.0f / NN);
    const float var = tot[128 + t] * (1.0f / NN) - m * m;
    const float rs = rsqrtf(var + BN_EPS);
    const float sc = rs * gamma[t];
    ss[t] = sc;
    ss[128 + t] = beta[t] - m * sc;
  }
}

__global__ __launch_bounds__(256)
void k_bn(float* __restrict__ h, float* __restrict__ out,
          const float* __restrict__ ss) {
  const int i4 = blockIdx.x * 256 + threadIdx.x;   // exactly N*D/4 threads
  const int c4 = (i4 & 31) * 4;
  const float4 sc = *(const float4*)&ss[c4];
  const float4 sh = *(const float4*)&ss[128 + c4];
  float4 hv = ((const float4*)h)[i4];
  float4 o;
  o.x = fmaf(hv.x, sc.x, sh.x);
  o.y = fmaf(hv.y, sc.y, sh.y);
  o.z = fmaf(hv.z, sc.z, sh.z);
  o.w = fmaf(hv.w, sc.w, sh.w);
  ((float4*)h)[i4] = o;
  float4 po = ((float4*)out)[i4];
  po.x += o.x; po.y += o.y; po.z += o.z; po.w += o.w;
  ((float4*)out)[i4] = po;
}

extern "C" void kernel_launch(void* const* d_in, const int* in_sizes, int n_in,
                              void* d_out, int out_size, void* d_ws, size_t ws_size,
                              hipStream_t stream) {
  const float* x = (const float*)d_in[0];
  const int* ei = (const int*)d_in[1];
  const float* W = (const float*)d_in[2];
  const float* b = (const float*)d_in[3];
  const float* gamma = (const float*)d_in[4];
  const float* beta = (const float*)d_in[5];
  float* out = (float*)d_out;
  const int* srcv = ei;
  const int* dstv = ei + EE;

  char* w = (char*)d_ws;
  int* rowptr = (int*)w;     w += (size_t)NPAD * 4;
  float* dinv = (float*)w;   w += (size_t)NPAD * 4;
  int* cntT = (int*)w;       w += (size_t)NBK * CSTRIDE * 4;
  int* baseT = (int*)w;      w += (size_t)NBK * CSTRIDE * 4;
  int* gtot = (int*)w;       w += 256 * 4;
  int* bktbase = (int*)w;    w += 260 * 4;
  int* col = (int*)w;        w += (size_t)EE * 4;
  float* ss = (float*)w;     w += 256 * 4;
  float* stat = (float*)w;   w += 256 * 4;
  unsigned short* Wt = (unsigned short*)w; w += (size_t)3 * DD * DD * 2;
  // ebuf (CSR-build only) aliases partials (spmm/bnred only); both 6.4 MB
  unsigned* ebuf = (unsigned*)w;
  float* partials = (float*)w; w += (size_t)EE * 4;
  float* bufA = (float*)w;   w += (size_t)NN * DD * 4;     // h (fp32)
  unsigned short* hsb = (unsigned short*)w;                // hs (bf16)

  hipMemcpyAsync(out, x, (size_t)NN * DD * sizeof(float),
                 hipMemcpyDeviceToDevice, stream);

  k_cnt<<<PART_GRID, 256, 0, stream>>>(dstv, cntT);
  k_colscan<<<NBK, 64, 0, stream>>>(cntT, baseT, gtot);
  k_bktscan<<<1, 64, 0, stream>>>(gtot, bktbase);
  k_part2<<<PART_GRID, 256, 0, stream>>>(srcv, dstv, baseT, bktbase, ebuf);
  k_csr2<<<NBK, 256, 0, stream>>>(ebuf, bktbase, rowptr, col, dinv);
  k_wt<<<3, 256, 0, stream>>>(W, Wt);

  const float* hcur = x;
  for (int l = 0; l < 3; ++l) {
    k_gemm<<<GEMM_GRID, 256, 0, stream>>>(hcur, Wt + (size_t)l * DD * DD,
                                          dinv, hsb);
    if (l < 2) {
      k_spmm<<<SPMM_GRID, 256, 0, stream>>>(hsb, rowptr, col, dinv,
                                            b + l * DD, bufA, nullptr,
                                            partials, 0);
      k_bnred<<<256, 256, 0, stream>>>(partials, stat);
      k_bnfin<<<1, 256, 0, stream>>>(stat, ss, gamma + l * DD, beta + l * DD);
      k_bn<<<(NN * DD / 4) / 256, 256, 0, stream>>>(bufA, out, ss);
      hcur = bufA;
    } else {
      k_spmm<<<SPMM_GRID, 256, 0, stream>>>(hsb, rowptr, col, dinv,
                                            b + l * DD, nullptr, out,
                                            nullptr, 1);
    }
  }
}

// Round 3
// 615.060 us; speedup vs baseline: 1.2124x; 1.1201x over previous
//
#include <hip/hip_runtime.h>
#include <hip/hip_bf16.h>

// GCN (3-layer, JK=sum) on MI355X.
// R9: (a) partials layout transposed to [blk][t] — mode-0 spmm WRITE_SIZE had
//     ~2x amplification (116MB vs 58MB logical) from 256-way 4B line-sharing
//     scatter; now one coalesced 1KB burst per block. (b) BN affine + JK-sum
//     folded into k_gemm A-fragment path: hbn = fmaf(h, sc[k], sh[k]) before
//     f2bf (bit-identical to old k_bn), out = x + h1bn at l=1 (replaces
//     memcpy; pure write), out += h2bn at l=2. Deletes k_bn (2 x 205MB) and
//     the 102MB memcpy -> ~307MB less traffic.
// R8: deterministic 2-pass LDS radix partition CSR build (no global atomics,
//     all coalesced). R7: GEMM via v_mfma_f32_16x16x32_bf16.

constexpr int NN = 100000;
constexpr int EE = 1600000;
constexpr int DD = 128;
constexpr float BN_EPS = 1e-5f;
constexpr int NPAD = 100096;
constexpr int SPMM_GRID = NN / 16;              // 6250
constexpr int GEMM_GRID = (NN + 63) / 64;       // 1563

// radix partition params
constexpr int NBK = (NN + 511) / 512;           // 196 coarse buckets (dst>>9)
constexpr int PB = 4096;                        // edges per partition block
constexpr int PART_GRID = (EE + PB - 1) / PB;   // 391
constexpr int CSTRIDE = 400;                    // >= PART_GRID, count-table stride
constexpr int CAPL = 10240;                     // LDS colseg capacity (mean 8192 + ~22 sigma)

typedef __attribute__((ext_vector_type(8))) short bf16x8;
typedef __attribute__((ext_vector_type(4))) float f32x4;

__device__ __forceinline__ float bfhi(unsigned int u) {
  union { unsigned int i; float f; } v; v.i = u & 0xffff0000u; return v.f;
}
__device__ __forceinline__ float bflo(unsigned int u) {
  union { unsigned int i; float f; } v; v.i = u << 16; return v.f;
}
__device__ __forceinline__ unsigned short f2bf(float f) {
  union { float f; unsigned int i; } v;
  v.f = f;
  unsigned int r = v.i + 0x7FFFu + ((v.i >> 16) & 1u);   // RNE
  return (unsigned short)(r >> 16);
}
__device__ __forceinline__ void acc8(uint4 u, float4& a0, float4& a1) {
  a0.x += bflo(u.x); a0.y += bfhi(u.x);
  a0.z += bflo(u.y); a0.w += bfhi(u.y);
  a1.x += bflo(u.z); a1.y += bfhi(u.z);
  a1.z += bflo(u.w); a1.w += bfhi(u.w);
}
__device__ __forceinline__ int wave_incl_scan(int v, int lane) {
#pragma unroll
  for (int off = 1; off < 64; off <<= 1) {
    int x = __shfl_up(v, off, 64);
    if (lane >= off) v += x;
  }
  return v;
}

// --- CSR build pass 1: per-(block,bucket) counts, transposed [bkt][blk] ---
__global__ __launch_bounds__(256)
void k_cnt(const int* __restrict__ dst, int* __restrict__ cntT) {
  __shared__ int cnt[256];
  const int t = threadIdx.x;
  const int e0 = blockIdx.x * PB;
  const int nv = min(PB, EE - e0);
  cnt[t] = 0;
  __syncthreads();
  for (int i = t; i < nv; i += 256)
    atomicAdd(&cnt[dst[e0 + i] >> 9], 1);
  __syncthreads();
  if (t < NBK) cntT[t * CSTRIDE + blockIdx.x] = cnt[t];
}

// --- per-bucket column scan over blocks ---
__global__ __launch_bounds__(64)
void k_colscan(const int* __restrict__ cntT, int* __restrict__ baseT,
               int* __restrict__ gtot) {
  const int b = blockIdx.x;
  const int lane = threadIdx.x;
  int c[7];
  int ls = 0;
#pragma unroll
  for (int j = 0; j < 7; ++j) {
    const int idx = lane * 7 + j;
    c[j] = (idx < PART_GRID) ? cntT[b * CSTRIDE + idx] : 0;
    ls += c[j];
  }
  const int is = wave_incl_scan(ls, lane);
  int run = is - ls;
#pragma unroll
  for (int j = 0; j < 7; ++j) {
    const int idx = lane * 7 + j;
    if (idx < PART_GRID) baseT[b * CSTRIDE + idx] = run;
    run += c[j];
  }
  if (lane == 63) gtot[b] = is;
}

// --- exclusive scan over 196 bucket totals -> bktbase[0..256] ---
__global__ __launch_bounds__(64)
void k_bktscan(const int* __restrict__ gtot, int* __restrict__ bktbase) {
  const int lane = threadIdx.x;
  int c[4];
  int ls = 0;
#pragma unroll
  for (int j = 0; j < 4; ++j) {
    const int idx = lane * 4 + j;
    c[j] = (idx < NBK) ? gtot[idx] : 0;
    ls += c[j];
  }
  const int is = wave_incl_scan(ls, lane);
  int run = is - ls;
#pragma unroll
  for (int j = 0; j < 4; ++j) {
    bktbase[lane * 4 + j] = run;
    run += c[j];
  }
  if (lane == 63) bktbase[256] = is;   // == EE
}

// --- CSR build pass 2: LDS counting sort per block, coalesced ebuf writes ---
__global__ __launch_bounds__(256)
void k_part2(const int* __restrict__ src, const int* __restrict__ dst,
             const int* __restrict__ baseT, const int* __restrict__ bktbase,
             unsigned* __restrict__ ebuf) {
  __shared__ unsigned sorted[PB];
  __shared__ unsigned char sortedb[PB];
  alignas(16) __shared__ int cnt[256];
  __shared__ int cur[256], start[256], gbase[256];
  const int t = threadIdx.x;
  const int lane = t & 63;
  const int e0 = blockIdx.x * PB;
  const int nv = min(PB, EE - e0);
  cnt[t] = 0;
  if (t < NBK) gbase[t] = bktbase[t] + baseT[t * CSTRIDE + blockIdx.x];
  __syncthreads();
  int es[PB / 256], ed[PB / 256];
#pragma unroll
  for (int j = 0; j < PB / 256; ++j) {
    const int i = t + j * 256;
    if (i < nv) {
      es[j] = src[e0 + i];
      ed[j] = dst[e0 + i];
      atomicAdd(&cnt[ed[j] >> 9], 1);
    } else {
      ed[j] = -1;
    }
  }
  __syncthreads();
  if (t < 64) {
    const int4 c = *(const int4*)&cnt[lane * 4];
    const int ls = c.x + c.y + c.z + c.w;
    const int is = wave_incl_scan(ls, lane);
    int run = is - ls;
    start[lane * 4] = run; cur[lane * 4] = run; run += c.x;
    start[lane * 4 + 1] = run; cur[lane * 4 + 1] = run; run += c.y;
    start[lane * 4 + 2] = run; cur[lane * 4 + 2] = run; run += c.z;
    start[lane * 4 + 3] = run; cur[lane * 4 + 3] = run;
  }
  __syncthreads();
#pragma unroll
  for (int j = 0; j < PB / 256; ++j) {
    if (ed[j] >= 0) {
      const int bkt = ed[j] >> 9;
      const int p = atomicAdd(&cur[bkt], 1);
      sorted[p] = ((unsigned)es[j] << 9) | (unsigned)(ed[j] & 511);
      sortedb[p] = (unsigned char)bkt;
    }
  }
  __syncthreads();
  for (int i = t; i < nv; i += 256) {
    const int bkt = sortedb[i];
    ebuf[(size_t)gbase[bkt] + (i - start[bkt])] = sorted[i];
  }
}

// --- CSR finish: one block per bucket, all writes coalesced ---
__global__ __launch_bounds__(256)
void k_csr2(const unsigned* __restrict__ ebuf, const int* __restrict__ bktbase,
            int* __restrict__ rowptr, int* __restrict__ col,
            float* __restrict__ dinv) {
  __shared__ int rowcnt[512], rowbase[512], rowcur[512];
  __shared__ unsigned colseg[CAPL];
  const int b = blockIdx.x;
  const int t = threadIdx.x;
  const int ebase = bktbase[b];
  const int n = min(bktbase[b + 1] - ebase, CAPL);
  const unsigned* eb = &ebuf[ebase];
  rowcnt[t] = 0;
  rowcnt[t + 256] = 0;
  __syncthreads();
  for (int i = t; i < n; i += 256)
    atomicAdd(&rowcnt[eb[i] & 511u], 1);
  __syncthreads();
  if (t < 64) {
    int v[8];
    int ls = 0;
#pragma unroll
    for (int j = 0; j < 8; ++j) { v[j] = rowcnt[t * 8 + j]; ls += v[j]; }
    const int is = wave_incl_scan(ls, t);
    int run = is - ls;
#pragma unroll
    for (int j = 0; j < 8; ++j) {
      rowbase[t * 8 + j] = run;
      rowcur[t * 8 + j] = run;
      run += v[j];
    }
  }
  __syncthreads();
#pragma unroll
  for (int h = 0; h < 2; ++h) {
    const int rl = t + h * 256;
    const int r = b * 512 + rl;
    if (r < NN) {
      rowptr[r] = ebase + rowbase[rl];
      dinv[r] = rsqrtf((float)rowcnt[rl] + 1.0f);
    }
  }
  if (b == NBK - 1 && t == 0) rowptr[NN] = ebase + n;
  for (int i = t; i < n; i += 256) {
    const unsigned u = eb[i];
    const int p = atomicAdd(&rowcur[u & 511u], 1);
    colseg[p] = u >> 9;
  }
  __syncthreads();
  for (int i = t; i < n; i += 256) col[ebase + i] = (int)colseg[i];
}

// --- W transpose+cvt: Wt[l][c][k] = bf16(W[l][k][c]) --- grid = 3 blocks
__global__ __launch_bounds__(256)
void k_wt(const float* __restrict__ W, unsigned short* __restrict__ Wt) {
  const float* Ws = W + (size_t)blockIdx.x * DD * DD;
  unsigned short* Wo = Wt + (size_t)blockIdx.x * DD * DD;
  for (int i = threadIdx.x; i < DD * DD; i += 256) {
    const int k = i >> 7, c = i & 127;
    Wo[c * DD + k] = f2bf(Ws[i]);
  }
}

// --- MFMA GEMM with fused BN affine + JK-sum accumulation.
//     ss != null: A-element = fmaf(h, ss[k], ss[128+k])  (BN of previous layer)
//     outmode 0: no out update; 1: out = addsrc + hbn; 2: out += hbn ---
__global__ __launch_bounds__(256)
void k_gemm(const float* __restrict__ h, const unsigned short* __restrict__ Wt,
            const float* __restrict__ dinv, unsigned short* __restrict__ hsb,
            const float* __restrict__ ss, const float* __restrict__ addsrc,
            float* __restrict__ out, const int outmode) {
  const int lane = threadIdx.x & 63;
  const int wave = threadIdx.x >> 6;          // 0..3
  const int n15 = lane & 15;
  const int quad = lane >> 4;                 // 0..3
  const int rbase = blockIdx.x * 64 + wave * 16;
  const int r0 = rbase + n15;
  const bool rowok = r0 < NN;
  const int arow = rowok ? r0 : NN - 1;       // clamped load row

  f32x4 acc[8];
#pragma unroll
  for (int ct = 0; ct < 8; ++ct) acc[ct] = (f32x4){0.f, 0.f, 0.f, 0.f};

#pragma unroll
  for (int kc = 0; kc < 4; ++kc) {
    const int k0 = kc * 32 + quad * 8;
    float4 a0 = *(const float4*)&h[(size_t)arow * DD + k0];
    float4 a1 = *(const float4*)&h[(size_t)arow * DD + k0 + 4];
    if (ss) {  // fused BatchNorm affine (bit-identical to old k_bn fmaf)
      const float4 sc0 = *(const float4*)&ss[k0];
      const float4 sc1 = *(const float4*)&ss[k0 + 4];
      const float4 sh0 = *(const float4*)&ss[128 + k0];
      const float4 sh1 = *(const float4*)&ss[128 + k0 + 4];
      a0.x = fmaf(a0.x, sc0.x, sh0.x); a0.y = fmaf(a0.y, sc0.y, sh0.y);
      a0.z = fmaf(a0.z, sc0.z, sh0.z); a0.w = fmaf(a0.w, sc0.w, sh0.w);
      a1.x = fmaf(a1.x, sc1.x, sh1.x); a1.y = fmaf(a1.y, sc1.y, sh1.y);
      a1.z = fmaf(a1.z, sc1.z, sh1.z); a1.w = fmaf(a1.w, sc1.w, sh1.w);
    }
    if (outmode == 1) {          // out = addsrc + hbn (pure write, JK init)
      if (rowok) {
        float4 x0 = *(const float4*)&addsrc[(size_t)arow * DD + k0];
        float4 x1 = *(const float4*)&addsrc[(size_t)arow * DD + k0 + 4];
        x0.x += a0.x; x0.y += a0.y; x0.z += a0.z; x0.w += a0.w;
        x1.x += a1.x; x1.y += a1.y; x1.z += a1.z; x1.w += a1.w;
        *(float4*)&out[(size_t)arow * DD + k0] = x0;
        *(float4*)&out[(size_t)arow * DD + k0 + 4] = x1;
      }
    } else if (outmode == 2) {   // out += hbn
      if (rowok) {
        float4 x0 = *(const float4*)&out[(size_t)arow * DD + k0];
        float4 x1 = *(const float4*)&out[(size_t)arow * DD + k0 + 4];
        x0.x += a0.x; x0.y += a0.y; x0.z += a0.z; x0.w += a0.w;
        x1.x += a1.x; x1.y += a1.y; x1.z += a1.z; x1.w += a1.w;
        *(float4*)&out[(size_t)arow * DD + k0] = x0;
        *(float4*)&out[(size_t)arow * DD + k0 + 4] = x1;
      }
    }
    bf16x8 af;
    af[0] = (short)f2bf(a0.x); af[1] = (short)f2bf(a0.y);
    af[2] = (short)f2bf(a0.z); af[3] = (short)f2bf(a0.w);
    af[4] = (short)f2bf(a1.x); af[5] = (short)f2bf(a1.y);
    af[6] = (short)f2bf(a1.z); af[7] = (short)f2bf(a1.w);
#pragma unroll
    for (int ct = 0; ct < 8; ++ct) {
      const bf16x8 bf = *(const bf16x8*)&Wt[(size_t)(ct * 16 + n15) * DD + k0];
      acc[ct] = __builtin_amdgcn_mfma_f32_16x16x32_bf16(af, bf, acc[ct], 0, 0, 0);
    }
  }

#pragma unroll
  for (int i = 0; i < 4; ++i) {
    const int r = rbase + quad * 4 + i;
    if (r < NN) {
      const float dv = dinv[r];
#pragma unroll
      for (int ct = 0; ct < 8; ++ct)
        hsb[(size_t)r * DD + ct * 16 + n15] = f2bf(acc[ct][i] * dv);
    }
  }
}

// --- SpMM; partials now coalesced [blk][t] ---
__global__ __launch_bounds__(256)
void k_spmm(const unsigned short* __restrict__ hsb, const int* __restrict__ rowptr,
            const int* __restrict__ col, const float* __restrict__ dinv,
            const float* __restrict__ bias, float* __restrict__ hout,
            float* __restrict__ out, float* __restrict__ partials,
            const int mode) {
  const int lane = threadIdx.x & 15;     // 16 lanes / row
  const int g = threadIdx.x >> 4;        // 0..15 rows / block
  const int c8 = lane * 8;
  const int d = blockIdx.x * 16 + g;
  float4 a0 = make_float4(0.f, 0.f, 0.f, 0.f);
  float4 a1 = make_float4(0.f, 0.f, 0.f, 0.f);
  float4 bs0 = a0, bs1 = a0, q0 = a0, q1 = a0;
  if (d < NN) {
    const unsigned short* rowp = &hsb[(size_t)d * DD + c8];
    acc8(*(const uint4*)rowp, a0, a1);                 // self-loop term
    int j = rowptr[d];
    const int e1 = rowptr[d + 1];
    for (; j + 3 < e1; j += 4) {
      const int s0 = col[j], s1 = col[j + 1], s2 = col[j + 2], s3 = col[j + 3];
      const uint4 u0 = *(const uint4*)&hsb[(size_t)s0 * DD + c8];
      const uint4 u1 = *(const uint4*)&hsb[(size_t)s1 * DD + c8];
      const uint4 u2 = *(const uint4*)&hsb[(size_t)s2 * DD + c8];
      const uint4 u3 = *(const uint4*)&hsb[(size_t)s3 * DD + c8];
      acc8(u0, a0, a1); acc8(u1, a0, a1);
      acc8(u2, a0, a1); acc8(u3, a0, a1);
    }
    for (; j < e1; ++j) {
      const uint4 u0 = *(const uint4*)&hsb[(size_t)col[j] * DD + c8];
      acc8(u0, a0, a1);
    }
    const float dv = dinv[d];
    const float4 b0 = *(const float4*)&bias[c8];
    const float4 b1 = *(const float4*)&bias[c8 + 4];
    float4 o0, o1;
    o0.x = fmaxf(fmaf(a0.x, dv, b0.x), 0.f);
    o0.y = fmaxf(fmaf(a0.y, dv, b0.y), 0.f);
    o0.z = fmaxf(fmaf(a0.z, dv, b0.z), 0.f);
    o0.w = fmaxf(fmaf(a0.w, dv, b0.w), 0.f);
    o1.x = fmaxf(fmaf(a1.x, dv, b1.x), 0.f);
    o1.y = fmaxf(fmaf(a1.y, dv, b1.y), 0.f);
    o1.z = fmaxf(fmaf(a1.z, dv, b1.z), 0.f);
    o1.w = fmaxf(fmaf(a1.w, dv, b1.w), 0.f);
    if (mode == 0) {
      *(float4*)&hout[(size_t)d * DD + c8] = o0;
      *(float4*)&hout[(size_t)d * DD + c8 + 4] = o1;
      bs0 = o0; bs1 = o1;
      q0.x = o0.x * o0.x; q0.y = o0.y * o0.y;
      q0.z = o0.z * o0.z; q0.w = o0.w * o0.w;
      q1.x = o1.x * o1.x; q1.y = o1.y * o1.y;
      q1.z = o1.z * o1.z; q1.w = o1.w * o1.w;
    } else {
      float4 p0 = *(const float4*)&out[(size_t)d * DD + c8];
      float4 p1 = *(const float4*)&out[(size_t)d * DD + c8 + 4];
      p0.x += o0.x; p0.y += o0.y; p0.z += o0.z; p0.w += o0.w;
      p1.x += o1.x; p1.y += o1.y; p1.z += o1.z; p1.w += o1.w;
      *(float4*)&out[(size_t)d * DD + c8] = p0;
      *(float4*)&out[(size_t)d * DD + c8 + 4] = p1;
    }
  }
  if (mode == 0) {
    __shared__ float red[256 * 16];
    float* my = &red[threadIdx.x * 16];
    my[0] = bs0.x; my[1] = bs0.y; my[2] = bs0.z; my[3] = bs0.w;
    my[4] = bs1.x; my[5] = bs1.y; my[6] = bs1.z; my[7] = bs1.w;
    my[8] = q0.x;  my[9] = q0.y;  my[10] = q0.z; my[11] = q0.w;
    my[12] = q1.x; my[13] = q1.y; my[14] = q1.z; my[15] = q1.w;
    __syncthreads();
    const int t = threadIdx.x;
    float s = 0.f;
#pragma unroll
    for (int gg = 0; gg < 16; ++gg) s += red[gg * 256 + t];
    partials[(size_t)blockIdx.x * 256 + t] = s;   // coalesced
  }
}

__global__ __launch_bounds__(256)
void k_bnred(const float* __restrict__ partials, float* __restrict__ stat) {
  __shared__ float s[256];
  const int slot = blockIdx.x;
  float v = 0.f;
  for (int i = threadIdx.x; i < SPMM_GRID; i += 256)
    v += partials[(size_t)i * 256 + slot];
  s[threadIdx.x] = v;
  __syncthreads();
  for (int off = 128; off; off >>= 1) {
    if (threadIdx.x < off) s[threadIdx.x] += s[threadIdx.x + off];
    __syncthreads();
  }
  if (threadIdx.x == 0) stat[slot] = s[0];
}

__global__ __launch_bounds__(256)
void k_bnfin(const float* __restrict__ stat, float* __restrict__ ss,
             const float* __restrict__ gamma, const float* __restrict__ beta) {
  __shared__ float tot[256];            // [kind*128 + c]
  const int t = threadIdx.x;
  const float s = stat[t];
  const int lane16 = t >> 4, q = t & 15;
  const int c = lane16 * 8 + (q & 7), kind = q >> 3;
  tot[kind * 128 + c] = s;
  __syncthreads();
  if (t < 128) {
    const float m = tot[t] * (1.0f / NN);
    const float var = tot[128 + t] * (1.0f / NN) - m * m;
    const float rs = rsqrtf(var + BN_EPS);
    const float sc = rs * gamma[t];
    ss[t] = sc;
    ss[128 + t] = beta[t] - m * sc;
  }
}

extern "C" void kernel_launch(void* const* d_in, const int* in_sizes, int n_in,
                              void* d_out, int out_size, void* d_ws, size_t ws_size,
                              hipStream_t stream) {
  const float* x = (const float*)d_in[0];
  const int* ei = (const int*)d_in[1];
  const float* W = (const float*)d_in[2];
  const float* b = (const float*)d_in[3];
  const float* gamma = (const float*)d_in[4];
  const float* beta = (const float*)d_in[5];
  float* out = (float*)d_out;
  const int* srcv = ei;
  const int* dstv = ei + EE;

  char* w = (char*)d_ws;
  int* rowptr = (int*)w;     w += (size_t)NPAD * 4;
  float* dinv = (float*)w;   w += (size_t)NPAD * 4;
  int* cntT = (int*)w;       w += (size_t)NBK * CSTRIDE * 4;
  int* baseT = (int*)w;      w += (size_t)NBK * CSTRIDE * 4;
  int* gtot = (int*)w;       w += 256 * 4;
  int* bktbase = (int*)w;    w += 260 * 4;
  int* col = (int*)w;        w += (size_t)EE * 4;
  float* ss = (float*)w;     w += 256 * 4;
  float* stat = (float*)w;   w += 256 * 4;
  unsigned short* Wt = (unsigned short*)w; w += (size_t)3 * DD * DD * 2;
  // ebuf (CSR-build only) aliases partials (spmm/bnred only); both 6.4 MB
  unsigned* ebuf = (unsigned*)w;
  float* partials = (float*)w; w += (size_t)EE * 4;
  float* bufA = (float*)w;   w += (size_t)NN * DD * 4;     // h (fp32)
  unsigned short* hsb = (unsigned short*)w;                // hs (bf16)

  k_cnt<<<PART_GRID, 256, 0, stream>>>(dstv, cntT);
  k_colscan<<<NBK, 64, 0, stream>>>(cntT, baseT, gtot);
  k_bktscan<<<1, 64, 0, stream>>>(gtot, bktbase);
  k_part2<<<PART_GRID, 256, 0, stream>>>(srcv, dstv, baseT, bktbase, ebuf);
  k_csr2<<<NBK, 256, 0, stream>>>(ebuf, bktbase, rowptr, col, dinv);
  k_wt<<<3, 256, 0, stream>>>(W, Wt);

  // l=0: A = x, no BN, no out update (out written first by l=1 gemm)
  k_gemm<<<GEMM_GRID, 256, 0, stream>>>(x, Wt, dinv, hsb,
                                        nullptr, nullptr, nullptr, 0);
  k_spmm<<<SPMM_GRID, 256, 0, stream>>>(hsb, rowptr, col, dinv,
                                        b, bufA, nullptr, partials, 0);
  k_bnred<<<256, 256, 0, stream>>>(partials, stat);
  k_bnfin<<<1, 256, 0, stream>>>(stat, ss, gamma, beta);

  // l=1: A = BN(h1) fused; out = x + h1bn (JK init, replaces memcpy)
  k_gemm<<<GEMM_GRID, 256, 0, stream>>>(bufA, Wt + (size_t)DD * DD, dinv, hsb,
                                        ss, x, out, 1);
  k_spmm<<<SPMM_GRID, 256, 0, stream>>>(hsb, rowptr, col, dinv,
                                        b + DD, bufA, nullptr, partials, 0);
  k_bnred<<<256, 256, 0, stream>>>(partials, stat);
  k_bnfin<<<1, 256, 0, stream>>>(stat, ss, gamma + DD, beta + DD);

  // l=2: A = BN(h2) fused; out += h2bn; spmm mode1 adds h3
  k_gemm<<<GEMM_GRID, 256, 0, stream>>>(bufA, Wt + (size_t)2 * DD * DD, dinv, hsb,
                                        ss, nullptr, out, 2);
  k_spmm<<<SPMM_GRID, 256, 0, stream>>>(hsb, rowptr, col, dinv,
                                        b + 2 * DD, nullptr, out,
                                        nullptr, 1);
}

// Round 5
// 585.206 us; speedup vs baseline: 1.2743x; 1.0510x over previous
//
#include <hip/hip_runtime.h>
#include <hip/hip_bf16.h>

// GCN (3-layer, JK=sum) on MI355X.
// R10b: identical resubmit of R10 (previous round died on GPU acquisition
//      timeout — infra, kernel never ran).
// R10: (a) inter-layer h stored bf16 (it is rounded to bf16 for the MFMA A
//      anyway): spmm mode-0 write 51.2->25.6MB, gemm l1/l2 A-read halved.
//      (b) spmm inner loop: dual accumulator pairs + 8-edge unroll — the old
//      4-edge/single-acc form had a fully serial 32-add chain between load
//      waits (VALUBusy 20%, latency-bound). Doubles outstanding gathers.
// R9: partials coalesced [blk][t]; BN affine + JK-sum folded into k_gemm.
// R8: deterministic 2-pass LDS radix partition CSR build.
// R7: GEMM via v_mfma_f32_16x16x32_bf16.

constexpr int NN = 100000;
constexpr int EE = 1600000;
constexpr int DD = 128;
constexpr float BN_EPS = 1e-5f;
constexpr int NPAD = 100096;
constexpr int SPMM_GRID = NN / 16;              // 6250
constexpr int GEMM_GRID = (NN + 63) / 64;       // 1563

// radix partition params
constexpr int NBK = (NN + 511) / 512;           // 196 coarse buckets (dst>>9)
constexpr int PB = 4096;                        // edges per partition block
constexpr int PART_GRID = (EE + PB - 1) / PB;   // 391
constexpr int CSTRIDE = 400;                    // >= PART_GRID, count-table stride
constexpr int CAPL = 10240;                     // LDS colseg capacity (mean 8192 + ~22 sigma)

typedef __attribute__((ext_vector_type(8))) short bf16x8;
typedef __attribute__((ext_vector_type(4))) float f32x4;

__device__ __forceinline__ float bfhi(unsigned int u) {
  union { unsigned int i; float f; } v; v.i = u & 0xffff0000u; return v.f;
}
__device__ __forceinline__ float bflo(unsigned int u) {
  union { unsigned int i; float f; } v; v.i = u << 16; return v.f;
}
__device__ __forceinline__ unsigned short f2bf(float f) {
  union { float f; unsigned int i; } v;
  v.f = f;
  unsigned int r = v.i + 0x7FFFu + ((v.i >> 16) & 1u);   // RNE
  return (unsigned short)(r >> 16);
}
__device__ __forceinline__ unsigned pack2(float lo, float hi) {
  return (unsigned)f2bf(lo) | ((unsigned)f2bf(hi) << 16);
}
__device__ __forceinline__ void acc8(uint4 u, float4& a0, float4& a1) {
  a0.x += bflo(u.x); a0.y += bfhi(u.x);
  a0.z += bflo(u.y); a0.w += bfhi(u.y);
  a1.x += bflo(u.z); a1.y += bfhi(u.z);
  a1.z += bflo(u.w); a1.w += bfhi(u.w);
}
__device__ __forceinline__ int wave_incl_scan(int v, int lane) {
#pragma unroll
  for (int off = 1; off < 64; off <<= 1) {
    int x = __shfl_up(v, off, 64);
    if (lane >= off) v += x;
  }
  return v;
}

// --- CSR build pass 1: per-(block,bucket) counts, transposed [bkt][blk] ---
__global__ __launch_bounds__(256)
void k_cnt(const int* __restrict__ dst, int* __restrict__ cntT) {
  __shared__ int cnt[256];
  const int t = threadIdx.x;
  const int e0 = blockIdx.x * PB;
  const int nv = min(PB, EE - e0);
  cnt[t] = 0;
  __syncthreads();
  for (int i = t; i < nv; i += 256)
    atomicAdd(&cnt[dst[e0 + i] >> 9], 1);
  __syncthreads();
  if (t < NBK) cntT[t * CSTRIDE + blockIdx.x] = cnt[t];
}

// --- per-bucket column scan over blocks ---
__global__ __launch_bounds__(64)
void k_colscan(const int* __restrict__ cntT, int* __restrict__ baseT,
               int* __restrict__ gtot) {
  const int b = blockIdx.x;
  const int lane = threadIdx.x;
  int c[7];
  int ls = 0;
#pragma unroll
  for (int j = 0; j < 7; ++j) {
    const int idx = lane * 7 + j;
    c[j] = (idx < PART_GRID) ? cntT[b * CSTRIDE + idx] : 0;
    ls += c[j];
  }
  const int is = wave_incl_scan(ls, lane);
  int run = is - ls;
#pragma unroll
  for (int j = 0; j < 7; ++j) {
    const int idx = lane * 7 + j;
    if (idx < PART_GRID) baseT[b * CSTRIDE + idx] = run;
    run += c[j];
  }
  if (lane == 63) gtot[b] = is;
}

// --- exclusive scan over 196 bucket totals -> bktbase[0..256] ---
__global__ __launch_bounds__(64)
void k_bktscan(const int* __restrict__ gtot, int* __restrict__ bktbase) {
  const int lane = threadIdx.x;
  int c[4];
  int ls = 0;
#pragma unroll
  for (int j = 0; j < 4; ++j) {
    const int idx = lane * 4 + j;
    c[j] = (idx < NBK) ? gtot[idx] : 0;
    ls += c[j];
  }
  const int is = wave_incl_scan(ls, lane);
  int run = is - ls;
#pragma unroll
  for (int j = 0; j < 4; ++j) {
    bktbase[lane * 4 + j] = run;
    run += c[j];
  }
  if (lane == 63) bktbase[256] = is;   // == EE
}

// --- CSR build pass 2: LDS counting sort per block, coalesced ebuf writes ---
__global__ __launch_bounds__(256)
void k_part2(const int* __restrict__ src, const int* __restrict__ dst,
             const int* __restrict__ baseT, const int* __restrict__ bktbase,
             unsigned* __restrict__ ebuf) {
  __shared__ unsigned sorted[PB];
  __shared__ unsigned char sortedb[PB];
  alignas(16) __shared__ int cnt[256];
  __shared__ int cur[256], start[256], gbase[256];
  const int t = threadIdx.x;
  const int lane = t & 63;
  const int e0 = blockIdx.x * PB;
  const int nv = min(PB, EE - e0);
  cnt[t] = 0;
  if (t < NBK) gbase[t] = bktbase[t] + baseT[t * CSTRIDE + blockIdx.x];
  __syncthreads();
  int es[PB / 256], ed[PB / 256];
#pragma unroll
  for (int j = 0; j < PB / 256; ++j) {
    const int i = t + j * 256;
    if (i < nv) {
      es[j] = src[e0 + i];
      ed[j] = dst[e0 + i];
      atomicAdd(&cnt[ed[j] >> 9], 1);
    } else {
      ed[j] = -1;
    }
  }
  __syncthreads();
  if (t < 64) {
    const int4 c = *(const int4*)&cnt[lane * 4];
    const int ls = c.x + c.y + c.z + c.w;
    const int is = wave_incl_scan(ls, lane);
    int run = is - ls;
    start[lane * 4] = run; cur[lane * 4] = run; run += c.x;
    start[lane * 4 + 1] = run; cur[lane * 4 + 1] = run; run += c.y;
    start[lane * 4 + 2] = run; cur[lane * 4 + 2] = run; run += c.z;
    start[lane * 4 + 3] = run; cur[lane * 4 + 3] = run;
  }
  __syncthreads();
#pragma unroll
  for (int j = 0; j < PB / 256; ++j) {
    if (ed[j] >= 0) {
      const int bkt = ed[j] >> 9;
      const int p = atomicAdd(&cur[bkt], 1);
      sorted[p] = ((unsigned)es[j] << 9) | (unsigned)(ed[j] & 511);
      sortedb[p] = (unsigned char)bkt;
    }
  }
  __syncthreads();
  for (int i = t; i < nv; i += 256) {
    const int bkt = sortedb[i];
    ebuf[(size_t)gbase[bkt] + (i - start[bkt])] = sorted[i];
  }
}

// --- CSR finish: one block per bucket, all writes coalesced ---
__global__ __launch_bounds__(256)
void k_csr2(const unsigned* __restrict__ ebuf, const int* __restrict__ bktbase,
            int* __restrict__ rowptr, int* __restrict__ col,
            float* __restrict__ dinv) {
  __shared__ int rowcnt[512], rowbase[512], rowcur[512];
  __shared__ unsigned colseg[CAPL];
  const int b = blockIdx.x;
  const int t = threadIdx.x;
  const int ebase = bktbase[b];
  const int n = min(bktbase[b + 1] - ebase, CAPL);
  const unsigned* eb = &ebuf[ebase];
  rowcnt[t] = 0;
  rowcnt[t + 256] = 0;
  __syncthreads();
  for (int i = t; i < n; i += 256)
    atomicAdd(&rowcnt[eb[i] & 511u], 1);
  __syncthreads();
  if (t < 64) {
    int v[8];
    int ls = 0;
#pragma unroll
    for (int j = 0; j < 8; ++j) { v[j] = rowcnt[t * 8 + j]; ls += v[j]; }
    const int is = wave_incl_scan(ls, t);
    int run = is - ls;
#pragma unroll
    for (int j = 0; j < 8; ++j) {
      rowbase[t * 8 + j] = run;
      rowcur[t * 8 + j] = run;
      run += v[j];
    }
  }
  __syncthreads();
#pragma unroll
  for (int h = 0; h < 2; ++h) {
    const int rl = t + h * 256;
    const int r = b * 512 + rl;
    if (r < NN) {
      rowptr[r] = ebase + rowbase[rl];
      dinv[r] = rsqrtf((float)rowcnt[rl] + 1.0f);
    }
  }
  if (b == NBK - 1 && t == 0) rowptr[NN] = ebase + n;
  for (int i = t; i < n; i += 256) {
    const unsigned u = eb[i];
    const int p = atomicAdd(&rowcur[u & 511u], 1);
    colseg[p] = u >> 9;
  }
  __syncthreads();
  for (int i = t; i < n; i += 256) col[ebase + i] = (int)colseg[i];
}

// --- W transpose+cvt: Wt[l][c][k] = bf16(W[l][k][c]) --- grid = 3 blocks
__global__ __launch_bounds__(256)
void k_wt(const float* __restrict__ W, unsigned short* __restrict__ Wt) {
  const float* Ws = W + (size_t)blockIdx.x * DD * DD;
  unsigned short* Wo = Wt + (size_t)blockIdx.x * DD * DD;
  for (int i = threadIdx.x; i < DD * DD; i += 256) {
    const int k = i >> 7, c = i & 127;
    Wo[c * DD + k] = f2bf(Ws[i]);
  }
}

// --- MFMA GEMM with fused BN affine + JK-sum accumulation.
//     A source: hf (fp32, layer 0) or hb (bf16, later layers) — exactly one
//     non-null. ss != null: A-element = fmaf(h, ss[k], ss[128+k]).
//     outmode 0: none; 1: out = addsrc + hbn; 2: out += hbn ---
__global__ __launch_bounds__(256)
void k_gemm(const float* __restrict__ hf, const unsigned short* __restrict__ hb,
            const unsigned short* __restrict__ Wt,
            const float* __restrict__ dinv, unsigned short* __restrict__ hsb,
            const float* __restrict__ ss, const float* __restrict__ addsrc,
            float* __restrict__ out, const int outmode) {
  const int lane = threadIdx.x & 63;
  const int wave = threadIdx.x >> 6;          // 0..3
  const int n15 = lane & 15;
  const int quad = lane >> 4;                 // 0..3
  const int rbase = blockIdx.x * 64 + wave * 16;
  const int r0 = rbase + n15;
  const bool rowok = r0 < NN;
  const int arow = rowok ? r0 : NN - 1;       // clamped load row

  f32x4 acc[8];
#pragma unroll
  for (int ct = 0; ct < 8; ++ct) acc[ct] = (f32x4){0.f, 0.f, 0.f, 0.f};

#pragma unroll
  for (int kc = 0; kc < 4; ++kc) {
    const int k0 = kc * 32 + quad * 8;
    float4 a0, a1;
    if (hb) {   // bf16 h (one 16B load covers all 8 elems)
      const uint4 u = *(const uint4*)&hb[(size_t)arow * DD + k0];
      a0.x = bflo(u.x); a0.y = bfhi(u.x);
      a0.z = bflo(u.y); a0.w = bfhi(u.y);
      a1.x = bflo(u.z); a1.y = bfhi(u.z);
      a1.z = bflo(u.w); a1.w = bfhi(u.w);
    } else {
      a0 = *(const float4*)&hf[(size_t)arow * DD + k0];
      a1 = *(const float4*)&hf[(size_t)arow * DD + k0 + 4];
    }
    if (ss) {  // fused BatchNorm affine
      const float4 sc0 = *(const float4*)&ss[k0];
      const float4 sc1 = *(const float4*)&ss[k0 + 4];
      const float4 sh0 = *(const float4*)&ss[128 + k0];
      const float4 sh1 = *(const float4*)&ss[128 + k0 + 4];
      a0.x = fmaf(a0.x, sc0.x, sh0.x); a0.y = fmaf(a0.y, sc0.y, sh0.y);
      a0.z = fmaf(a0.z, sc0.z, sh0.z); a0.w = fmaf(a0.w, sc0.w, sh0.w);
      a1.x = fmaf(a1.x, sc1.x, sh1.x); a1.y = fmaf(a1.y, sc1.y, sh1.y);
      a1.z = fmaf(a1.z, sc1.z, sh1.z); a1.w = fmaf(a1.w, sc1.w, sh1.w);
    }
    if (outmode == 1) {          // out = addsrc + hbn (pure write, JK init)
      if (rowok) {
        float4 x0 = *(const float4*)&addsrc[(size_t)arow * DD + k0];
        float4 x1 = *(const float4*)&addsrc[(size_t)arow * DD + k0 + 4];
        x0.x += a0.x; x0.y += a0.y; x0.z += a0.z; x0.w += a0.w;
        x1.x += a1.x; x1.y += a1.y; x1.z += a1.z; x1.w += a1.w;
        *(float4*)&out[(size_t)arow * DD + k0] = x0;
        *(float4*)&out[(size_t)arow * DD + k0 + 4] = x1;
      }
    } else if (outmode == 2) {   // out += hbn
      if (rowok) {
        float4 x0 = *(const float4*)&out[(size_t)arow * DD + k0];
        float4 x1 = *(const float4*)&out[(size_t)arow * DD + k0 + 4];
        x0.x += a0.x; x0.y += a0.y; x0.z += a0.z; x0.w += a0.w;
        x1.x += a1.x; x1.y += a1.y; x1.z += a1.z; x1.w += a1.w;
        *(float4*)&out[(size_t)arow * DD + k0] = x0;
        *(float4*)&out[(size_t)arow * DD + k0 + 4] = x1;
      }
    }
    bf16x8 af;
    af[0] = (short)f2bf(a0.x); af[1] = (short)f2bf(a0.y);
    af[2] = (short)f2bf(a0.z); af[3] = (short)f2bf(a0.w);
    af[4] = (short)f2bf(a1.x); af[5] = (short)f2bf(a1.y);
    af[6] = (short)f2bf(a1.z); af[7] = (short)f2bf(a1.w);
#pragma unroll
    for (int ct = 0; ct < 8; ++ct) {
      const bf16x8 bf = *(const bf16x8*)&Wt[(size_t)(ct * 16 + n15) * DD + k0];
      acc[ct] = __builtin_amdgcn_mfma_f32_16x16x32_bf16(af, bf, acc[ct], 0, 0, 0);
    }
  }

#pragma unroll
  for (int i = 0; i < 4; ++i) {
    const int r = rbase + quad * 4 + i;
    if (r < NN) {
      const float dv = dinv[r];
#pragma unroll
      for (int ct = 0; ct < 8; ++ct)
        hsb[(size_t)r * DD + ct * 16 + n15] = f2bf(acc[ct][i] * dv);
    }
  }
}

// --- SpMM: dual accumulator pairs, 8-edge unroll; bf16 hout ---
__global__ __launch_bounds__(256)
void k_spmm(const unsigned short* __restrict__ hsb, const int* __restrict__ rowptr,
            const int* __restrict__ col, const float* __restrict__ dinv,
            const float* __restrict__ bias, unsigned short* __restrict__ hout,
            float* __restrict__ out, float* __restrict__ partials,
            const int mode) {
  const int lane = threadIdx.x & 15;     // 16 lanes / row
  const int g = threadIdx.x >> 4;        // 0..15 rows / block
  const int c8 = lane * 8;
  const int d = blockIdx.x * 16 + g;
  float4 a0 = make_float4(0.f, 0.f, 0.f, 0.f);
  float4 a1 = make_float4(0.f, 0.f, 0.f, 0.f);
  float4 c0 = a0, c1 = a0;               // second accumulator pair
  float4 bs0 = a0, bs1 = a0, q0 = a0, q1 = a0;
  if (d < NN) {
    const unsigned short* rowp = &hsb[(size_t)d * DD + c8];
    acc8(*(const uint4*)rowp, a0, a1);                 // self-loop term
    int j = rowptr[d];
    const int e1 = rowptr[d + 1];
    for (; j + 7 < e1; j += 8) {
      const int s0 = col[j],     s1 = col[j + 1], s2 = col[j + 2], s3 = col[j + 3];
      const int s4 = col[j + 4], s5 = col[j + 5], s6 = col[j + 6], s7 = col[j + 7];
      const uint4 u0 = *(const uint4*)&hsb[(size_t)s0 * DD + c8];
      const uint4 u1 = *(const uint4*)&hsb[(size_t)s1 * DD + c8];
      const uint4 u2 = *(const uint4*)&hsb[(size_t)s2 * DD + c8];
      const uint4 u3 = *(const uint4*)&hsb[(size_t)s3 * DD + c8];
      const uint4 u4 = *(const uint4*)&hsb[(size_t)s4 * DD + c8];
      const uint4 u5 = *(const uint4*)&hsb[(size_t)s5 * DD + c8];
      const uint4 u6 = *(const uint4*)&hsb[(size_t)s6 * DD + c8];
      const uint4 u7 = *(const uint4*)&hsb[(size_t)s7 * DD + c8];
      acc8(u0, a0, a1); acc8(u1, c0, c1);
      acc8(u2, a0, a1); acc8(u3, c0, c1);
      acc8(u4, a0, a1); acc8(u5, c0, c1);
      acc8(u6, a0, a1); acc8(u7, c0, c1);
    }
    for (; j + 3 < e1; j += 4) {
      const int s0 = col[j], s1 = col[j + 1], s2 = col[j + 2], s3 = col[j + 3];
      const uint4 u0 = *(const uint4*)&hsb[(size_t)s0 * DD + c8];
      const uint4 u1 = *(const uint4*)&hsb[(size_t)s1 * DD + c8];
      const uint4 u2 = *(const uint4*)&hsb[(size_t)s2 * DD + c8];
      const uint4 u3 = *(const uint4*)&hsb[(size_t)s3 * DD + c8];
      acc8(u0, a0, a1); acc8(u1, c0, c1);
      acc8(u2, a0, a1); acc8(u3, c0, c1);
    }
    for (; j < e1; ++j) {
      const uint4 u0 = *(const uint4*)&hsb[(size_t)col[j] * DD + c8];
      acc8(u0, a0, a1);
    }
    a0.x += c0.x; a0.y += c0.y; a0.z += c0.z; a0.w += c0.w;
    a1.x += c1.x; a1.y += c1.y; a1.z += c1.z; a1.w += c1.w;
    const float dv = dinv[d];
    const float4 bb0 = *(const float4*)&bias[c8];
    const float4 bb1 = *(const float4*)&bias[c8 + 4];
    float4 o0, o1;
    o0.x = fmaxf(fmaf(a0.x, dv, bb0.x), 0.f);
    o0.y = fmaxf(fmaf(a0.y, dv, bb0.y), 0.f);
    o0.z = fmaxf(fmaf(a0.z, dv, bb0.z), 0.f);
    o0.w = fmaxf(fmaf(a0.w, dv, bb0.w), 0.f);
    o1.x = fmaxf(fmaf(a1.x, dv, bb1.x), 0.f);
    o1.y = fmaxf(fmaf(a1.y, dv, bb1.y), 0.f);
    o1.z = fmaxf(fmaf(a1.z, dv, bb1.z), 0.f);
    o1.w = fmaxf(fmaf(a1.w, dv, bb1.w), 0.f);
    if (mode == 0) {
      uint4 pk;
      pk.x = pack2(o0.x, o0.y); pk.y = pack2(o0.z, o0.w);
      pk.z = pack2(o1.x, o1.y); pk.w = pack2(o1.z, o1.w);
      *(uint4*)&hout[(size_t)d * DD + c8] = pk;       // bf16 h for next gemm
      bs0 = o0; bs1 = o1;
      q0.x = o0.x * o0.x; q0.y = o0.y * o0.y;
      q0.z = o0.z * o0.z; q0.w = o0.w * o0.w;
      q1.x = o1.x * o1.x; q1.y = o1.y * o1.y;
      q1.z = o1.z * o1.z; q1.w = o1.w * o1.w;
    } else {
      float4 p0 = *(const float4*)&out[(size_t)d * DD + c8];
      float4 p1 = *(const float4*)&out[(size_t)d * DD + c8 + 4];
      p0.x += o0.x; p0.y += o0.y; p0.z += o0.z; p0.w += o0.w;
      p1.x += o1.x; p1.y += o1.y; p1.z += o1.z; p1.w += o1.w;
      *(float4*)&out[(size_t)d * DD + c8] = p0;
      *(float4*)&out[(size_t)d * DD + c8 + 4] = p1;
    }
  }
  if (mode == 0) {
    __shared__ float red[256 * 16];
    float* my = &red[threadIdx.x * 16];
    my[0] = bs0.x; my[1] = bs0.y; my[2] = bs0.z; my[3] = bs0.w;
    my[4] = bs1.x; my[5] = bs1.y; my[6] = bs1.z; my[7] = bs1.w;
    my[8] = q0.x;  my[9] = q0.y;  my[10] = q0.z; my[11] = q0.w;
    my[12] = q1.x; my[13] = q1.y; my[14] = q1.z; my[15] = q1.w;
    __syncthreads();
    const int t = threadIdx.x;
    float s = 0.f;
#pragma unroll
    for (int gg = 0; gg < 16; ++gg) s += red[gg * 256 + t];
    partials[(size_t)blockIdx.x * 256 + t] = s;   // coalesced
  }
}

__global__ __launch_bounds__(256)
void k_bnred(const float* __restrict__ partials, float* __restrict__ stat) {
  __shared__ float s[256];
  const int slot = blockIdx.x;
  float v = 0.f;
  for (int i = threadIdx.x; i < SPMM_GRID; i += 256)
    v += partials[(size_t)i * 256 + slot];
  s[threadIdx.x] = v;
  __syncthreads();
  for (int off = 128; off; off >>= 1) {
    if (threadIdx.x < off) s[threadIdx.x] += s[threadIdx.x + off];
    __syncthreads();
  }
  if (threadIdx.x == 0) stat[slot] = s[0];
}

__global__ __launch_bounds__(256)
void k_bnfin(const float* __restrict__ stat, float* __restrict__ ss,
             const float* __restrict__ gamma, const float* __restrict__ beta) {
  __shared__ float tot[256];            // [kind*128 + c]
  const int t = threadIdx.x;
  const float s = stat[t];
  const int lane16 = t >> 4, q = t & 15;
  const int c = lane16 * 8 + (q & 7), kind = q >> 3;
  tot[kind * 128 + c] = s;
  __syncthreads();
  if (t < 128) {
    const float m = tot[t] * (1.0f / NN);
    const float var = tot[128 + t] * (1.0f / NN) - m * m;
    const float rs = rsqrtf(var + BN_EPS);
    const float sc = rs * gamma[t];
    ss[t] = sc;
    ss[128 + t] = beta[t] - m * sc;
  }
}

extern "C" void kernel_launch(void* const* d_in, const int* in_sizes, int n_in,
                              void* d_out, int out_size, void* d_ws, size_t ws_size,
                              hipStream_t stream) {
  const float* x = (const float*)d_in[0];
  const int* ei = (const int*)d_in[1];
  const float* W = (const float*)d_in[2];
  const float* b = (const float*)d_in[3];
  const float* gamma = (const float*)d_in[4];
  const float* beta = (const float*)d_in[5];
  float* out = (float*)d_out;
  const int* srcv = ei;
  const int* dstv = ei + EE;

  char* w = (char*)d_ws;
  int* rowptr = (int*)w;     w += (size_t)NPAD * 4;
  float* dinv = (float*)w;   w += (size_t)NPAD * 4;
  int* cntT = (int*)w;       w += (size_t)NBK * CSTRIDE * 4;
  int* baseT = (int*)w;      w += (size_t)NBK * CSTRIDE * 4;
  int* gtot = (int*)w;       w += 256 * 4;
  int* bktbase = (int*)w;    w += 260 * 4;
  int* col = (int*)w;        w += (size_t)EE * 4;
  float* ss = (float*)w;     w += 256 * 4;
  float* stat = (float*)w;   w += 256 * 4;
  unsigned short* Wt = (unsigned short*)w; w += (size_t)3 * DD * DD * 2;
  // ebuf (CSR-build only) aliases partials (spmm/bnred only); both 6.4 MB
  unsigned* ebuf = (unsigned*)w;
  float* partials = (float*)w; w += (size_t)EE * 4;
  unsigned short* hbuf = (unsigned short*)w; w += (size_t)NN * DD * 2;  // h (bf16)
  unsigned short* hsb = (unsigned short*)w;                             // hs (bf16)

  k_cnt<<<PART_GRID, 256, 0, stream>>>(dstv, cntT);
  k_colscan<<<NBK, 64, 0, stream>>>(cntT, baseT, gtot);
  k_bktscan<<<1, 64, 0, stream>>>(gtot, bktbase);
  k_part2<<<PART_GRID, 256, 0, stream>>>(srcv, dstv, baseT, bktbase, ebuf);
  k_csr2<<<NBK, 256, 0, stream>>>(ebuf, bktbase, rowptr, col, dinv);
  k_wt<<<3, 256, 0, stream>>>(W, Wt);

  // l=0: A = x (fp32), no BN, no out update
  k_gemm<<<GEMM_GRID, 256, 0, stream>>>(x, nullptr, Wt, dinv, hsb,
                                        nullptr, nullptr, nullptr, 0);
  k_spmm<<<SPMM_GRID, 256, 0, stream>>>(hsb, rowptr, col, dinv,
                                        b, hbuf, nullptr, partials, 0);
  k_bnred<<<256, 256, 0, stream>>>(partials, stat);
  k_bnfin<<<1, 256, 0, stream>>>(stat, ss, gamma, beta);

  // l=1: A = BN(h1) fused (bf16 h); out = x + h1bn (JK init)
  k_gemm<<<GEMM_GRID, 256, 0, stream>>>(nullptr, hbuf, Wt + (size_t)DD * DD,
                                        dinv, hsb, ss, x, out, 1);
  k_spmm<<<SPMM_GRID, 256, 0, stream>>>(hsb, rowptr, col, dinv,
                                        b + DD, hbuf, nullptr, partials, 0);
  k_bnred<<<256, 256, 0, stream>>>(partials, stat);
  k_bnfin<<<1, 256, 0, stream>>>(stat, ss, gamma + DD, beta + DD);

  // l=2: A = BN(h2) fused (bf16 h); out += h2bn; spmm mode1 adds h3
  k_gemm<<<GEMM_GRID, 256, 0, stream>>>(nullptr, hbuf, Wt + (size_t)2 * DD * DD,
                                        dinv, hsb, ss, nullptr, out, 2);
  k_spmm<<<SPMM_GRID, 256, 0, stream>>>(hsb, rowptr, col, dinv,
                                        b + 2 * DD, nullptr, out,
                                        nullptr, 1);
}

// Round 6
// 570.625 us; speedup vs baseline: 1.3068x; 1.0256x over previous
//
#include <hip/hip_runtime.h>
#include <hip/hip_bf16.h>

// GCN (3-layer, JK=sum) on MI355X.
// R11: JK-sum deferred entirely to the final spmm epilogue:
//      out = ((x + BN1(h1)) + BN2(h2)) + h3, same fp32 add order as R10.
//      Deletes l1-gemm's x-read/out-write and l2-gemm's out R+W (−204.8MB)
//      at the cost of x/h1b/h2b reads in the final spmm (+102.4MB read,
//      −51.2MB out-read there). Net −153.6MB. h1,h2 kept in separate bf16
//      buffers; BN scale/shift for both layers kept (ss[512]).
// R10: inter-layer h bf16; spmm dual-acc 8-edge unroll.
// R9: partials coalesced [blk][t]; BN affine fused into gemm A-path.
// R8: deterministic 2-pass LDS radix partition CSR build.
// R7: GEMM via v_mfma_f32_16x16x32_bf16.

constexpr int NN = 100000;
constexpr int EE = 1600000;
constexpr int DD = 128;
constexpr float BN_EPS = 1e-5f;
constexpr int NPAD = 100096;
constexpr int SPMM_GRID = NN / 16;              // 6250
constexpr int GEMM_GRID = (NN + 63) / 64;       // 1563

// radix partition params
constexpr int NBK = (NN + 511) / 512;           // 196 coarse buckets (dst>>9)
constexpr int PB = 4096;                        // edges per partition block
constexpr int PART_GRID = (EE + PB - 1) / PB;   // 391
constexpr int CSTRIDE = 400;                    // >= PART_GRID, count-table stride
constexpr int CAPL = 10240;                     // LDS colseg capacity (mean 8192 + ~22 sigma)

typedef __attribute__((ext_vector_type(8))) short bf16x8;
typedef __attribute__((ext_vector_type(4))) float f32x4;

__device__ __forceinline__ float bfhi(unsigned int u) {
  union { unsigned int i; float f; } v; v.i = u & 0xffff0000u; return v.f;
}
__device__ __forceinline__ float bflo(unsigned int u) {
  union { unsigned int i; float f; } v; v.i = u << 16; return v.f;
}
__device__ __forceinline__ unsigned short f2bf(float f) {
  union { float f; unsigned int i; } v;
  v.f = f;
  unsigned int r = v.i + 0x7FFFu + ((v.i >> 16) & 1u);   // RNE
  return (unsigned short)(r >> 16);
}
__device__ __forceinline__ unsigned pack2(float lo, float hi) {
  return (unsigned)f2bf(lo) | ((unsigned)f2bf(hi) << 16);
}
__device__ __forceinline__ void acc8(uint4 u, float4& a0, float4& a1) {
  a0.x += bflo(u.x); a0.y += bfhi(u.x);
  a0.z += bflo(u.y); a0.w += bfhi(u.y);
  a1.x += bflo(u.z); a1.y += bfhi(u.z);
  a1.z += bflo(u.w); a1.w += bfhi(u.w);
}
__device__ __forceinline__ int wave_incl_scan(int v, int lane) {
#pragma unroll
  for (int off = 1; off < 64; off <<= 1) {
    int x = __shfl_up(v, off, 64);
    if (lane >= off) v += x;
  }
  return v;
}

// --- CSR build pass 1: per-(block,bucket) counts, transposed [bkt][blk] ---
__global__ __launch_bounds__(256)
void k_cnt(const int* __restrict__ dst, int* __restrict__ cntT) {
  __shared__ int cnt[256];
  const int t = threadIdx.x;
  const int e0 = blockIdx.x * PB;
  const int nv = min(PB, EE - e0);
  cnt[t] = 0;
  __syncthreads();
  for (int i = t; i < nv; i += 256)
    atomicAdd(&cnt[dst[e0 + i] >> 9], 1);
  __syncthreads();
  if (t < NBK) cntT[t * CSTRIDE + blockIdx.x] = cnt[t];
}

// --- per-bucket column scan over blocks ---
__global__ __launch_bounds__(64)
void k_colscan(const int* __restrict__ cntT, int* __restrict__ baseT,
               int* __restrict__ gtot) {
  const int b = blockIdx.x;
  const int lane = threadIdx.x;
  int c[7];
  int ls = 0;
#pragma unroll
  for (int j = 0; j < 7; ++j) {
    const int idx = lane * 7 + j;
    c[j] = (idx < PART_GRID) ? cntT[b * CSTRIDE + idx] : 0;
    ls += c[j];
  }
  const int is = wave_incl_scan(ls, lane);
  int run = is - ls;
#pragma unroll
  for (int j = 0; j < 7; ++j) {
    const int idx = lane * 7 + j;
    if (idx < PART_GRID) baseT[b * CSTRIDE + idx] = run;
    run += c[j];
  }
  if (lane == 63) gtot[b] = is;
}

// --- exclusive scan over 196 bucket totals -> bktbase[0..256] ---
__global__ __launch_bounds__(64)
void k_bktscan(const int* __restrict__ gtot, int* __restrict__ bktbase) {
  const int lane = threadIdx.x;
  int c[4];
  int ls = 0;
#pragma unroll
  for (int j = 0; j < 4; ++j) {
    const int idx = lane * 4 + j;
    c[j] = (idx < NBK) ? gtot[idx] : 0;
    ls += c[j];
  }
  const int is = wave_incl_scan(ls, lane);
  int run = is - ls;
#pragma unroll
  for (int j = 0; j < 4; ++j) {
    bktbase[lane * 4 + j] = run;
    run += c[j];
  }
  if (lane == 63) bktbase[256] = is;   // == EE
}

// --- CSR build pass 2: LDS counting sort per block, coalesced ebuf writes ---
__global__ __launch_bounds__(256)
void k_part2(const int* __restrict__ src, const int* __restrict__ dst,
             const int* __restrict__ baseT, const int* __restrict__ bktbase,
             unsigned* __restrict__ ebuf) {
  __shared__ unsigned sorted[PB];
  __shared__ unsigned char sortedb[PB];
  alignas(16) __shared__ int cnt[256];
  __shared__ int cur[256], start[256], gbase[256];
  const int t = threadIdx.x;
  const int lane = t & 63;
  const int e0 = blockIdx.x * PB;
  const int nv = min(PB, EE - e0);
  cnt[t] = 0;
  if (t < NBK) gbase[t] = bktbase[t] + baseT[t * CSTRIDE + blockIdx.x];
  __syncthreads();
  int es[PB / 256], ed[PB / 256];
#pragma unroll
  for (int j = 0; j < PB / 256; ++j) {
    const int i = t + j * 256;
    if (i < nv) {
      es[j] = src[e0 + i];
      ed[j] = dst[e0 + i];
      atomicAdd(&cnt[ed[j] >> 9], 1);
    } else {
      ed[j] = -1;
    }
  }
  __syncthreads();
  if (t < 64) {
    const int4 c = *(const int4*)&cnt[lane * 4];
    const int ls = c.x + c.y + c.z + c.w;
    const int is = wave_incl_scan(ls, lane);
    int run = is - ls;
    start[lane * 4] = run; cur[lane * 4] = run; run += c.x;
    start[lane * 4 + 1] = run; cur[lane * 4 + 1] = run; run += c.y;
    start[lane * 4 + 2] = run; cur[lane * 4 + 2] = run; run += c.z;
    start[lane * 4 + 3] = run; cur[lane * 4 + 3] = run;
  }
  __syncthreads();
#pragma unroll
  for (int j = 0; j < PB / 256; ++j) {
    if (ed[j] >= 0) {
      const int bkt = ed[j] >> 9;
      const int p = atomicAdd(&cur[bkt], 1);
      sorted[p] = ((unsigned)es[j] << 9) | (unsigned)(ed[j] & 511);
      sortedb[p] = (unsigned char)bkt;
    }
  }
  __syncthreads();
  for (int i = t; i < nv; i += 256) {
    const int bkt = sortedb[i];
    ebuf[(size_t)gbase[bkt] + (i - start[bkt])] = sorted[i];
  }
}

// --- CSR finish: one block per bucket, all writes coalesced ---
__global__ __launch_bounds__(256)
void k_csr2(const unsigned* __restrict__ ebuf, const int* __restrict__ bktbase,
            int* __restrict__ rowptr, int* __restrict__ col,
            float* __restrict__ dinv) {
  __shared__ int rowcnt[512], rowbase[512], rowcur[512];
  __shared__ unsigned colseg[CAPL];
  const int b = blockIdx.x;
  const int t = threadIdx.x;
  const int ebase = bktbase[b];
  const int n = min(bktbase[b + 1] - ebase, CAPL);
  const unsigned* eb = &ebuf[ebase];
  rowcnt[t] = 0;
  rowcnt[t + 256] = 0;
  __syncthreads();
  for (int i = t; i < n; i += 256)
    atomicAdd(&rowcnt[eb[i] & 511u], 1);
  __syncthreads();
  if (t < 64) {
    int v[8];
    int ls = 0;
#pragma unroll
    for (int j = 0; j < 8; ++j) { v[j] = rowcnt[t * 8 + j]; ls += v[j]; }
    const int is = wave_incl_scan(ls, t);
    int run = is - ls;
#pragma unroll
    for (int j = 0; j < 8; ++j) {
      rowbase[t * 8 + j] = run;
      rowcur[t * 8 + j] = run;
      run += v[j];
    }
  }
  __syncthreads();
#pragma unroll
  for (int h = 0; h < 2; ++h) {
    const int rl = t + h * 256;
    const int r = b * 512 + rl;
    if (r < NN) {
      rowptr[r] = ebase + rowbase[rl];
      dinv[r] = rsqrtf((float)rowcnt[rl] + 1.0f);
    }
  }
  if (b == NBK - 1 && t == 0) rowptr[NN] = ebase + n;
  for (int i = t; i < n; i += 256) {
    const unsigned u = eb[i];
    const int p = atomicAdd(&rowcur[u & 511u], 1);
    colseg[p] = u >> 9;
  }
  __syncthreads();
  for (int i = t; i < n; i += 256) col[ebase + i] = (int)colseg[i];
}

// --- W transpose+cvt: Wt[l][c][k] = bf16(W[l][k][c]) --- grid = 3 blocks
__global__ __launch_bounds__(256)
void k_wt(const float* __restrict__ W, unsigned short* __restrict__ Wt) {
  const float* Ws = W + (size_t)blockIdx.x * DD * DD;
  unsigned short* Wo = Wt + (size_t)blockIdx.x * DD * DD;
  for (int i = threadIdx.x; i < DD * DD; i += 256) {
    const int k = i >> 7, c = i & 127;
    Wo[c * DD + k] = f2bf(Ws[i]);
  }
}

// --- MFMA GEMM with optional fused BN affine on A.
//     A source: hf (fp32) or hb (bf16) — exactly one non-null.
//     ss != null: A-element = fmaf(h, ss[k], ss[128+k]). ---
__global__ __launch_bounds__(256)
void k_gemm(const float* __restrict__ hf, const unsigned short* __restrict__ hb,
            const unsigned short* __restrict__ Wt,
            const float* __restrict__ dinv, unsigned short* __restrict__ hsb,
            const float* __restrict__ ss) {
  const int lane = threadIdx.x & 63;
  const int wave = threadIdx.x >> 6;          // 0..3
  const int n15 = lane & 15;
  const int quad = lane >> 4;                 // 0..3
  const int rbase = blockIdx.x * 64 + wave * 16;
  const int r0 = rbase + n15;
  const int arow = (r0 < NN) ? r0 : NN - 1;   // clamped load row

  f32x4 acc[8];
#pragma unroll
  for (int ct = 0; ct < 8; ++ct) acc[ct] = (f32x4){0.f, 0.f, 0.f, 0.f};

#pragma unroll
  for (int kc = 0; kc < 4; ++kc) {
    const int k0 = kc * 32 + quad * 8;
    float4 a0, a1;
    if (hb) {   // bf16 h (one 16B load covers all 8 elems)
      const uint4 u = *(const uint4*)&hb[(size_t)arow * DD + k0];
      a0.x = bflo(u.x); a0.y = bfhi(u.x);
      a0.z = bflo(u.y); a0.w = bfhi(u.y);
      a1.x = bflo(u.z); a1.y = bfhi(u.z);
      a1.z = bflo(u.w); a1.w = bfhi(u.w);
    } else {
      a0 = *(const float4*)&hf[(size_t)arow * DD + k0];
      a1 = *(const float4*)&hf[(size_t)arow * DD + k0 + 4];
    }
    if (ss) {  // fused BatchNorm affine
      const float4 sc0 = *(const float4*)&ss[k0];
      const float4 sc1 = *(const float4*)&ss[k0 + 4];
      const float4 sh0 = *(const float4*)&ss[128 + k0];
      const float4 sh1 = *(const float4*)&ss[128 + k0 + 4];
      a0.x = fmaf(a0.x, sc0.x, sh0.x); a0.y = fmaf(a0.y, sc0.y, sh0.y);
      a0.z = fmaf(a0.z, sc0.z, sh0.z); a0.w = fmaf(a0.w, sc0.w, sh0.w);
      a1.x = fmaf(a1.x, sc1.x, sh1.x); a1.y = fmaf(a1.y, sc1.y, sh1.y);
      a1.z = fmaf(a1.z, sc1.z, sh1.z); a1.w = fmaf(a1.w, sc1.w, sh1.w);
    }
    bf16x8 af;
    af[0] = (short)f2bf(a0.x); af[1] = (short)f2bf(a0.y);
    af[2] = (short)f2bf(a0.z); af[3] = (short)f2bf(a0.w);
    af[4] = (short)f2bf(a1.x); af[5] = (short)f2bf(a1.y);
    af[6] = (short)f2bf(a1.z); af[7] = (short)f2bf(a1.w);
#pragma unroll
    for (int ct = 0; ct < 8; ++ct) {
      const bf16x8 bf = *(const bf16x8*)&Wt[(size_t)(ct * 16 + n15) * DD + k0];
      acc[ct] = __builtin_amdgcn_mfma_f32_16x16x32_bf16(af, bf, acc[ct], 0, 0, 0);
    }
  }

#pragma unroll
  for (int i = 0; i < 4; ++i) {
    const int r = rbase + quad * 4 + i;
    if (r < NN) {
      const float dv = dinv[r];
#pragma unroll
      for (int ct = 0; ct < 8; ++ct)
        hsb[(size_t)r * DD + ct * 16 + n15] = f2bf(acc[ct][i] * dv);
    }
  }
}

// --- SpMM: dual accumulator pairs, 8-edge unroll.
//     mode 0: hout = bf16(relu(...)), partials for BN stats.
//     mode 1: out = ((x + BN1(h1)) + BN2(h2)) + relu(...)  (full JK sum) ---
__global__ __launch_bounds__(256)
void k_spmm(const unsigned short* __restrict__ hsb, const int* __restrict__ rowptr,
            const int* __restrict__ col, const float* __restrict__ dinv,
            const float* __restrict__ bias, unsigned short* __restrict__ hout,
            float* __restrict__ partials, const float* __restrict__ x,
            const unsigned short* __restrict__ h1b,
            const unsigned short* __restrict__ h2b,
            const float* __restrict__ ss, float* __restrict__ out,
            const int mode) {
  const int lane = threadIdx.x & 15;     // 16 lanes / row
  const int g = threadIdx.x >> 4;        // 0..15 rows / block
  const int c8 = lane * 8;
  const int d = blockIdx.x * 16 + g;
  float4 a0 = make_float4(0.f, 0.f, 0.f, 0.f);
  float4 a1 = make_float4(0.f, 0.f, 0.f, 0.f);
  float4 c0 = a0, c1 = a0;               // second accumulator pair
  float4 bs0 = a0, bs1 = a0, q0 = a0, q1 = a0;
  if (d < NN) {
    const unsigned short* rowp = &hsb[(size_t)d * DD + c8];
    acc8(*(const uint4*)rowp, a0, a1);                 // self-loop term
    int j = rowptr[d];
    const int e1 = rowptr[d + 1];
    for (; j + 7 < e1; j += 8) {
      const int s0 = col[j],     s1 = col[j + 1], s2 = col[j + 2], s3 = col[j + 3];
      const int s4 = col[j + 4], s5 = col[j + 5], s6 = col[j + 6], s7 = col[j + 7];
      const uint4 u0 = *(const uint4*)&hsb[(size_t)s0 * DD + c8];
      const uint4 u1 = *(const uint4*)&hsb[(size_t)s1 * DD + c8];
      const uint4 u2 = *(const uint4*)&hsb[(size_t)s2 * DD + c8];
      const uint4 u3 = *(const uint4*)&hsb[(size_t)s3 * DD + c8];
      const uint4 u4 = *(const uint4*)&hsb[(size_t)s4 * DD + c8];
      const uint4 u5 = *(const uint4*)&hsb[(size_t)s5 * DD + c8];
      const uint4 u6 = *(const uint4*)&hsb[(size_t)s6 * DD + c8];
      const uint4 u7 = *(const uint4*)&hsb[(size_t)s7 * DD + c8];
      acc8(u0, a0, a1); acc8(u1, c0, c1);
      acc8(u2, a0, a1); acc8(u3, c0, c1);
      acc8(u4, a0, a1); acc8(u5, c0, c1);
      acc8(u6, a0, a1); acc8(u7, c0, c1);
    }
    for (; j + 3 < e1; j += 4) {
      const int s0 = col[j], s1 = col[j + 1], s2 = col[j + 2], s3 = col[j + 3];
      const uint4 u0 = *(const uint4*)&hsb[(size_t)s0 * DD + c8];
      const uint4 u1 = *(const uint4*)&hsb[(size_t)s1 * DD + c8];
      const uint4 u2 = *(const uint4*)&hsb[(size_t)s2 * DD + c8];
      const uint4 u3 = *(const uint4*)&hsb[(size_t)s3 * DD + c8];
      acc8(u0, a0, a1); acc8(u1, c0, c1);
      acc8(u2, a0, a1); acc8(u3, c0, c1);
    }
    for (; j < e1; ++j) {
      const uint4 u0 = *(const uint4*)&hsb[(size_t)col[j] * DD + c8];
      acc8(u0, a0, a1);
    }
    a0.x += c0.x; a0.y += c0.y; a0.z += c0.z; a0.w += c0.w;
    a1.x += c1.x; a1.y += c1.y; a1.z += c1.z; a1.w += c1.w;
    const float dv = dinv[d];
    const float4 bb0 = *(const float4*)&bias[c8];
    const float4 bb1 = *(const float4*)&bias[c8 + 4];
    float4 o0, o1;
    o0.x = fmaxf(fmaf(a0.x, dv, bb0.x), 0.f);
    o0.y = fmaxf(fmaf(a0.y, dv, bb0.y), 0.f);
    o0.z = fmaxf(fmaf(a0.z, dv, bb0.z), 0.f);
    o0.w = fmaxf(fmaf(a0.w, dv, bb0.w), 0.f);
    o1.x = fmaxf(fmaf(a1.x, dv, bb1.x), 0.f);
    o1.y = fmaxf(fmaf(a1.y, dv, bb1.y), 0.f);
    o1.z = fmaxf(fmaf(a1.z, dv, bb1.z), 0.f);
    o1.w = fmaxf(fmaf(a1.w, dv, bb1.w), 0.f);
    if (mode == 0) {
      uint4 pk;
      pk.x = pack2(o0.x, o0.y); pk.y = pack2(o0.z, o0.w);
      pk.z = pack2(o1.x, o1.y); pk.w = pack2(o1.z, o1.w);
      *(uint4*)&hout[(size_t)d * DD + c8] = pk;       // bf16 h for next gemm
      bs0 = o0; bs1 = o1;
      q0.x = o0.x * o0.x; q0.y = o0.y * o0.y;
      q0.z = o0.z * o0.z; q0.w = o0.w * o0.w;
      q1.x = o1.x * o1.x; q1.y = o1.y * o1.y;
      q1.z = o1.z * o1.z; q1.w = o1.w * o1.w;
    } else {
      // full JK sum: ((x + BN1(h1)) + BN2(h2)) + h3, same order as R10
      float4 v0 = *(const float4*)&x[(size_t)d * DD + c8];
      float4 v1 = *(const float4*)&x[(size_t)d * DD + c8 + 4];
      const uint4 uh1 = *(const uint4*)&h1b[(size_t)d * DD + c8];
      const uint4 uh2 = *(const uint4*)&h2b[(size_t)d * DD + c8];
      {
        const float4 sc0 = *(const float4*)&ss[c8];
        const float4 sc1 = *(const float4*)&ss[c8 + 4];
        const float4 sh0 = *(const float4*)&ss[128 + c8];
        const float4 sh1 = *(const float4*)&ss[128 + c8 + 4];
        v0.x += fmaf(bflo(uh1.x), sc0.x, sh0.x);
        v0.y += fmaf(bfhi(uh1.x), sc0.y, sh0.y);
        v0.z += fmaf(bflo(uh1.y), sc0.z, sh0.z);
        v0.w += fmaf(bfhi(uh1.y), sc0.w, sh0.w);
        v1.x += fmaf(bflo(uh1.z), sc1.x, sh1.x);
        v1.y += fmaf(bfhi(uh1.z), sc1.y, sh1.y);
        v1.z += fmaf(bflo(uh1.w), sc1.z, sh1.z);
        v1.w += fmaf(bfhi(uh1.w), sc1.w, sh1.w);
      }
      {
        const float4 sc0 = *(const float4*)&ss[256 + c8];
        const float4 sc1 = *(const float4*)&ss[256 + c8 + 4];
        const float4 sh0 = *(const float4*)&ss[384 + c8];
        const float4 sh1 = *(const float4*)&ss[384 + c8 + 4];
        v0.x += fmaf(bflo(uh2.x), sc0.x, sh0.x);
        v0.y += fmaf(bfhi(uh2.x), sc0.y, sh0.y);
        v0.z += fmaf(bflo(uh2.y), sc0.z, sh0.z);
        v0.w += fmaf(bfhi(uh2.y), sc0.w, sh0.w);
        v1.x += fmaf(bflo(uh2.z), sc1.x, sh1.x);
        v1.y += fmaf(bfhi(uh2.z), sc1.y, sh1.y);
        v1.z += fmaf(bflo(uh2.w), sc1.z, sh1.z);
        v1.w += fmaf(bfhi(uh2.w), sc1.w, sh1.w);
      }
      v0.x += o0.x; v0.y += o0.y; v0.z += o0.z; v0.w += o0.w;
      v1.x += o1.x; v1.y += o1.y; v1.z += o1.z; v1.w += o1.w;
      *(float4*)&out[(size_t)d * DD + c8] = v0;
      *(float4*)&out[(size_t)d * DD + c8 + 4] = v1;
    }
  }
  if (mode == 0) {
    __shared__ float red[256 * 16];
    float* my = &red[threadIdx.x * 16];
    my[0] = bs0.x; my[1] = bs0.y; my[2] = bs0.z; my[3] = bs0.w;
    my[4] = bs1.x; my[5] = bs1.y; my[6] = bs1.z; my[7] = bs1.w;
    my[8] = q0.x;  my[9] = q0.y;  my[10] = q0.z; my[11] = q0.w;
    my[12] = q1.x; my[13] = q1.y; my[14] = q1.z; my[15] = q1.w;
    __syncthreads();
    const int t = threadIdx.x;
    float s = 0.f;
#pragma unroll
    for (int gg = 0; gg < 16; ++gg) s += red[gg * 256 + t];
    partials[(size_t)blockIdx.x * 256 + t] = s;   // coalesced
  }
}

__global__ __launch_bounds__(256)
void k_bnred(const float* __restrict__ partials, float* __restrict__ stat) {
  __shared__ float s[256];
  const int slot = blockIdx.x;
  float v = 0.f;
  for (int i = threadIdx.x; i < SPMM_GRID; i += 256)
    v += partials[(size_t)i * 256 + slot];
  s[threadIdx.x] = v;
  __syncthreads();
  for (int off = 128; off; off >>= 1) {
    if (threadIdx.x < off) s[threadIdx.x] += s[threadIdx.x + off];
    __syncthreads();
  }
  if (threadIdx.x == 0) stat[slot] = s[0];
}

__global__ __launch_bounds__(256)
void k_bnfin(const float* __restrict__ stat, float* __restrict__ ss,
             const float* __restrict__ gamma, const float* __restrict__ beta) {
  __shared__ float tot[256];            // [kind*128 + c]
  const int t = threadIdx.x;
  const float s = stat[t];
  const int lane16 = t >> 4, q = t & 15;
  const int c = lane16 * 8 + (q & 7), kind = q >> 3;
  tot[kind * 128 + c] = s;
  __syncthreads();
  if (t < 128) {
    const float m = tot[t] * (1.0f / NN);
    const float var = tot[128 + t] * (1.0f / NN) - m * m;
    const float rs = rsqrtf(var + BN_EPS);
    const float sc = rs * gamma[t];
    ss[t] = sc;
    ss[128 + t] = beta[t] - m * sc;
  }
}

extern "C" void kernel_launch(void* const* d_in, const int* in_sizes, int n_in,
                              void* d_out, int out_size, void* d_ws, size_t ws_size,
                              hipStream_t stream) {
  const float* x = (const float*)d_in[0];
  const int* ei = (const int*)d_in[1];
  const float* W = (const float*)d_in[2];
  const float* b = (const float*)d_in[3];
  const float* gamma = (const float*)d_in[4];
  const float* beta = (const float*)d_in[5];
  float* out = (float*)d_out;
  const int* srcv = ei;
  const int* dstv = ei + EE;

  char* w = (char*)d_ws;
  int* rowptr = (int*)w;     w += (size_t)NPAD * 4;
  float* dinv = (float*)w;   w += (size_t)NPAD * 4;
  int* cntT = (int*)w;       w += (size_t)NBK * CSTRIDE * 4;
  int* baseT = (int*)w;      w += (size_t)NBK * CSTRIDE * 4;
  int* gtot = (int*)w;       w += 256 * 4;
  int* bktbase = (int*)w;    w += 260 * 4;
  int* col = (int*)w;        w += (size_t)EE * 4;
  float* ss = (float*)w;     w += 512 * 4;        // [l][scale|shift] x2 layers
  float* stat = (float*)w;   w += 256 * 4;
  unsigned short* Wt = (unsigned short*)w; w += (size_t)3 * DD * DD * 2;
  // ebuf (CSR-build only) aliases partials (spmm/bnred only); both 6.4 MB
  unsigned* ebuf = (unsigned*)w;
  float* partials = (float*)w; w += (size_t)EE * 4;
  unsigned short* h1b = (unsigned short*)w; w += (size_t)NN * DD * 2;  // h1 (bf16)
  unsigned short* h2b = (unsigned short*)w; w += (size_t)NN * DD * 2;  // h2 (bf16)
  unsigned short* hsb = (unsigned short*)w;                            // hs (bf16)

  k_cnt<<<PART_GRID, 256, 0, stream>>>(dstv, cntT);
  k_colscan<<<NBK, 64, 0, stream>>>(cntT, baseT, gtot);
  k_bktscan<<<1, 64, 0, stream>>>(gtot, bktbase);
  k_part2<<<PART_GRID, 256, 0, stream>>>(srcv, dstv, baseT, bktbase, ebuf);
  k_csr2<<<NBK, 256, 0, stream>>>(ebuf, bktbase, rowptr, col, dinv);
  k_wt<<<3, 256, 0, stream>>>(W, Wt);

  // l=0: A = x (fp32), no BN
  k_gemm<<<GEMM_GRID, 256, 0, stream>>>(x, nullptr, Wt, dinv, hsb, nullptr);
  k_spmm<<<SPMM_GRID, 256, 0, stream>>>(hsb, rowptr, col, dinv, b,
                                        h1b, partials,
                                        nullptr, nullptr, nullptr, nullptr,
                                        nullptr, 0);
  k_bnred<<<256, 256, 0, stream>>>(partials, stat);
  k_bnfin<<<1, 256, 0, stream>>>(stat, ss, gamma, beta);

  // l=1: A = BN1(h1) fused (bf16)
  k_gemm<<<GEMM_GRID, 256, 0, stream>>>(nullptr, h1b, Wt + (size_t)DD * DD,
                                        dinv, hsb, ss);
  k_spmm<<<SPMM_GRID, 256, 0, stream>>>(hsb, rowptr, col, dinv, b + DD,
                                        h2b, partials,
                                        nullptr, nullptr, nullptr, nullptr,
                                        nullptr, 0);
  k_bnred<<<256, 256, 0, stream>>>(partials, stat);
  k_bnfin<<<1, 256, 0, stream>>>(stat, ss + 256, gamma + DD, beta + DD);

  // l=2: A = BN2(h2) fused (bf16); final spmm does the whole JK sum
  k_gemm<<<GEMM_GRID, 256, 0, stream>>>(nullptr, h2b, Wt + (size_t)2 * DD * DD,
                                        dinv, hsb, ss + 256);
  k_spmm<<<SPMM_GRID, 256, 0, stream>>>(hsb, rowptr, col, dinv, b + 2 * DD,
                                        nullptr, nullptr,
                                        x, h1b, h2b, ss, out, 1);
}

// Round 8
// 500.960 us; speedup vs baseline: 1.4886x; 1.1391x over previous
//
#include <hip/hip_runtime.h>
#include <hip/hip_bf16.h>

// GCN (3-layer, JK=sum) on MI355X.
// R13: hsb stored int8 with PER-ROW scale (scale[r]=rowmax/127, 400KB table,
//      L2-resident). R12's fp8 e4m3 halved gather bytes but added 0.69 absmax
//      (3-bit mantissa: ~0.022 abs err on row-max values x 17-neighbor sums).
//      int8+row-scale keeps the 128B gather granule but is 8x better
//      worst-case error (rowmax/254 ~ 0.0028/elem) -> predicted absmax ~0.25
//      vs threshold 0.3775. Rowmax via 8 local fabs + 4 shfl_xor in gemm
//      epilogue; decode = bfe+cvt+fma (VALU 21% has headroom).
// R11: JK-sum deferred to final spmm epilogue (out = ((x+BN1h1)+BN2h2)+h3).
// R10: inter-layer h bf16; spmm dual-acc 8-edge unroll.
// R9: partials coalesced [blk][t]; BN affine fused into gemm A-path.
// R8: deterministic 2-pass LDS radix partition CSR build.
// R7: GEMM via v_mfma_f32_16x16x32_bf16.

constexpr int NN = 100000;
constexpr int EE = 1600000;
constexpr int DD = 128;
constexpr float BN_EPS = 1e-5f;
constexpr int NPAD = 100096;
constexpr int SPMM_GRID = NN / 16;              // 6250
constexpr int GEMM_GRID = (NN + 63) / 64;       // 1563

// radix partition params
constexpr int NBK = (NN + 511) / 512;           // 196 coarse buckets (dst>>9)
constexpr int PB = 4096;                        // edges per partition block
constexpr int PART_GRID = (EE + PB - 1) / PB;   // 391
constexpr int CSTRIDE = 400;                    // >= PART_GRID, count-table stride
constexpr int CAPL = 10240;                     // LDS colseg capacity (mean 8192 + ~22 sigma)

typedef __attribute__((ext_vector_type(8))) short bf16x8;
typedef __attribute__((ext_vector_type(4))) float f32x4;

__device__ __forceinline__ float bfhi(unsigned int u) {
  union { unsigned int i; float f; } v; v.i = u & 0xffff0000u; return v.f;
}
__device__ __forceinline__ float bflo(unsigned int u) {
  union { unsigned int i; float f; } v; v.i = u << 16; return v.f;
}
__device__ __forceinline__ unsigned short f2bf(float f) {
  union { float f; unsigned int i; } v;
  v.f = f;
  unsigned int r = v.i + 0x7FFFu + ((v.i >> 16) & 1u);   // RNE
  return (unsigned short)(r >> 16);
}
__device__ __forceinline__ unsigned pack2(float lo, float hi) {
  return (unsigned)f2bf(lo) | ((unsigned)f2bf(hi) << 16);
}
// int8 row-scaled decode: 8 channels from one uint2, scale sc
__device__ __forceinline__ void acci8(uint2 u, float sc, float4& a0, float4& a1) {
  a0.x += sc * (float)(int)(signed char)(u.x & 0xffu);
  a0.y += sc * (float)(int)(signed char)((u.x >> 8) & 0xffu);
  a0.z += sc * (float)(int)(signed char)((u.x >> 16) & 0xffu);
  a0.w += sc * (float)(int)(signed char)(u.x >> 24);
  a1.x += sc * (float)(int)(signed char)(u.y & 0xffu);
  a1.y += sc * (float)(int)(signed char)((u.y >> 8) & 0xffu);
  a1.z += sc * (float)(int)(signed char)((u.y >> 16) & 0xffu);
  a1.w += sc * (float)(int)(signed char)(u.y >> 24);
}
__device__ __forceinline__ int wave_incl_scan(int v, int lane) {
#pragma unroll
  for (int off = 1; off < 64; off <<= 1) {
    int x = __shfl_up(v, off, 64);
    if (lane >= off) v += x;
  }
  return v;
}

// --- CSR build pass 1: per-(block,bucket) counts, transposed [bkt][blk] ---
__global__ __launch_bounds__(256)
void k_cnt(const int* __restrict__ dst, int* __restrict__ cntT) {
  __shared__ int cnt[256];
  const int t = threadIdx.x;
  const int e0 = blockIdx.x * PB;
  const int nv = min(PB, EE - e0);
  cnt[t] = 0;
  __syncthreads();
  for (int i = t; i < nv; i += 256)
    atomicAdd(&cnt[dst[e0 + i] >> 9], 1);
  __syncthreads();
  if (t < NBK) cntT[t * CSTRIDE + blockIdx.x] = cnt[t];
}

// --- per-bucket column scan over blocks ---
__global__ __launch_bounds__(64)
void k_colscan(const int* __restrict__ cntT, int* __restrict__ baseT,
               int* __restrict__ gtot) {
  const int b = blockIdx.x;
  const int lane = threadIdx.x;
  int c[7];
  int ls = 0;
#pragma unroll
  for (int j = 0; j < 7; ++j) {
    const int idx = lane * 7 + j;
    c[j] = (idx < PART_GRID) ? cntT[b * CSTRIDE + idx] : 0;
    ls += c[j];
  }
  const int is = wave_incl_scan(ls, lane);
  int run = is - ls;
#pragma unroll
  for (int j = 0; j < 7; ++j) {
    const int idx = lane * 7 + j;
    if (idx < PART_GRID) baseT[b * CSTRIDE + idx] = run;
    run += c[j];
  }
  if (lane == 63) gtot[b] = is;
}

// --- exclusive scan over 196 bucket totals -> bktbase[0..256] ---
__global__ __launch_bounds__(64)
void k_bktscan(const int* __restrict__ gtot, int* __restrict__ bktbase) {
  const int lane = threadIdx.x;
  int c[4];
  int ls = 0;
#pragma unroll
  for (int j = 0; j < 4; ++j) {
    const int idx = lane * 4 + j;
    c[j] = (idx < NBK) ? gtot[idx] : 0;
    ls += c[j];
  }
  const int is = wave_incl_scan(ls, lane);
  int run = is - ls;
#pragma unroll
  for (int j = 0; j < 4; ++j) {
    bktbase[lane * 4 + j] = run;
    run += c[j];
  }
  if (lane == 63) bktbase[256] = is;   // == EE
}

// --- CSR build pass 2: LDS counting sort per block, coalesced ebuf writes ---
__global__ __launch_bounds__(256)
void k_part2(const int* __restrict__ src, const int* __restrict__ dst,
             const int* __restrict__ baseT, const int* __restrict__ bktbase,
             unsigned* __restrict__ ebuf) {
  __shared__ unsigned sorted[PB];
  __shared__ unsigned char sortedb[PB];
  alignas(16) __shared__ int cnt[256];
  __shared__ int cur[256], start[256], gbase[256];
  const int t = threadIdx.x;
  const int lane = t & 63;
  const int e0 = blockIdx.x * PB;
  const int nv = min(PB, EE - e0);
  cnt[t] = 0;
  if (t < NBK) gbase[t] = bktbase[t] + baseT[t * CSTRIDE + blockIdx.x];
  __syncthreads();
  int es[PB / 256], ed[PB / 256];
#pragma unroll
  for (int j = 0; j < PB / 256; ++j) {
    const int i = t + j * 256;
    if (i < nv) {
      es[j] = src[e0 + i];
      ed[j] = dst[e0 + i];
      atomicAdd(&cnt[ed[j] >> 9], 1);
    } else {
      ed[j] = -1;
    }
  }
  __syncthreads();
  if (t < 64) {
    const int4 c = *(const int4*)&cnt[lane * 4];
    const int ls = c.x + c.y + c.z + c.w;
    const int is = wave_incl_scan(ls, lane);
    int run = is - ls;
    start[lane * 4] = run; cur[lane * 4] = run; run += c.x;
    start[lane * 4 + 1] = run; cur[lane * 4 + 1] = run; run += c.y;
    start[lane * 4 + 2] = run; cur[lane * 4 + 2] = run; run += c.z;
    start[lane * 4 + 3] = run; cur[lane * 4 + 3] = run;
  }
  __syncthreads();
#pragma unroll
  for (int j = 0; j < PB / 256; ++j) {
    if (ed[j] >= 0) {
      const int bkt = ed[j] >> 9;
      const int p = atomicAdd(&cur[bkt], 1);
      sorted[p] = ((unsigned)es[j] << 9) | (unsigned)(ed[j] & 511);
      sortedb[p] = (unsigned char)bkt;
    }
  }
  __syncthreads();
  for (int i = t; i < nv; i += 256) {
    const int bkt = sortedb[i];
    ebuf[(size_t)gbase[bkt] + (i - start[bkt])] = sorted[i];
  }
}

// --- CSR finish: one block per bucket, all writes coalesced ---
__global__ __launch_bounds__(256)
void k_csr2(const unsigned* __restrict__ ebuf, const int* __restrict__ bktbase,
            int* __restrict__ rowptr, int* __restrict__ col,
            float* __restrict__ dinv) {
  __shared__ int rowcnt[512], rowbase[512], rowcur[512];
  __shared__ unsigned colseg[CAPL];
  const int b = blockIdx.x;
  const int t = threadIdx.x;
  const int ebase = bktbase[b];
  const int n = min(bktbase[b + 1] - ebase, CAPL);
  const unsigned* eb = &ebuf[ebase];
  rowcnt[t] = 0;
  rowcnt[t + 256] = 0;
  __syncthreads();
  for (int i = t; i < n; i += 256)
    atomicAdd(&rowcnt[eb[i] & 511u], 1);
  __syncthreads();
  if (t < 64) {
    int v[8];
    int ls = 0;
#pragma unroll
    for (int j = 0; j < 8; ++j) { v[j] = rowcnt[t * 8 + j]; ls += v[j]; }
    const int is = wave_incl_scan(ls, t);
    int run = is - ls;
#pragma unroll
    for (int j = 0; j < 8; ++j) {
      rowbase[t * 8 + j] = run;
      rowcur[t * 8 + j] = run;
      run += v[j];
    }
  }
  __syncthreads();
#pragma unroll
  for (int h = 0; h < 2; ++h) {
    const int rl = t + h * 256;
    const int r = b * 512 + rl;
    if (r < NN) {
      rowptr[r] = ebase + rowbase[rl];
      dinv[r] = rsqrtf((float)rowcnt[rl] + 1.0f);
    }
  }
  if (b == NBK - 1 && t == 0) rowptr[NN] = ebase + n;
  for (int i = t; i < n; i += 256) {
    const unsigned u = eb[i];
    const int p = atomicAdd(&rowcur[u & 511u], 1);
    colseg[p] = u >> 9;
  }
  __syncthreads();
  for (int i = t; i < n; i += 256) col[ebase + i] = (int)colseg[i];
}

// --- W transpose+cvt: Wt[l][c][k] = bf16(W[l][k][c]) --- grid = 3 blocks
__global__ __launch_bounds__(256)
void k_wt(const float* __restrict__ W, unsigned short* __restrict__ Wt) {
  const float* Ws = W + (size_t)blockIdx.x * DD * DD;
  unsigned short* Wo = Wt + (size_t)blockIdx.x * DD * DD;
  for (int i = threadIdx.x; i < DD * DD; i += 256) {
    const int k = i >> 7, c = i & 127;
    Wo[c * DD + k] = f2bf(Ws[i]);
  }
}

// --- MFMA GEMM with optional fused BN affine on A; int8+row-scale output.
//     A source: hf (fp32) or hb (bf16) — exactly one non-null.
//     ss != null: A-element = fmaf(h, ss[k], ss[128+k]). ---
__global__ __launch_bounds__(256)
void k_gemm(const float* __restrict__ hf, const unsigned short* __restrict__ hb,
            const unsigned short* __restrict__ Wt,
            const float* __restrict__ dinv, unsigned char* __restrict__ hs8,
            float* __restrict__ scalev, const float* __restrict__ ss) {
  const int lane = threadIdx.x & 63;
  const int wave = threadIdx.x >> 6;          // 0..3
  const int n15 = lane & 15;
  const int quad = lane >> 4;                 // 0..3
  const int rbase = blockIdx.x * 64 + wave * 16;
  const int r0 = rbase + n15;
  const int arow = (r0 < NN) ? r0 : NN - 1;   // clamped load row

  f32x4 acc[8];
#pragma unroll
  for (int ct = 0; ct < 8; ++ct) acc[ct] = (f32x4){0.f, 0.f, 0.f, 0.f};

#pragma unroll
  for (int kc = 0; kc < 4; ++kc) {
    const int k0 = kc * 32 + quad * 8;
    float4 a0, a1;
    if (hb) {   // bf16 h (one 16B load covers all 8 elems)
      const uint4 u = *(const uint4*)&hb[(size_t)arow * DD + k0];
      a0.x = bflo(u.x); a0.y = bfhi(u.x);
      a0.z = bflo(u.y); a0.w = bfhi(u.y);
      a1.x = bflo(u.z); a1.y = bfhi(u.z);
      a1.z = bflo(u.w); a1.w = bfhi(u.w);
    } else {
      a0 = *(const float4*)&hf[(size_t)arow * DD + k0];
      a1 = *(const float4*)&hf[(size_t)arow * DD + k0 + 4];
    }
    if (ss) {  // fused BatchNorm affine
      const float4 sc0 = *(const float4*)&ss[k0];
      const float4 sc1 = *(const float4*)&ss[k0 + 4];
      const float4 sh0 = *(const float4*)&ss[128 + k0];
      const float4 sh1 = *(const float4*)&ss[128 + k0 + 4];
      a0.x = fmaf(a0.x, sc0.x, sh0.x); a0.y = fmaf(a0.y, sc0.y, sh0.y);
      a0.z = fmaf(a0.z, sc0.z, sh0.z); a0.w = fmaf(a0.w, sc0.w, sh0.w);
      a1.x = fmaf(a1.x, sc1.x, sh1.x); a1.y = fmaf(a1.y, sc1.y, sh1.y);
      a1.z = fmaf(a1.z, sc1.z, sh1.z); a1.w = fmaf(a1.w, sc1.w, sh1.w);
    }
    bf16x8 af;
    af[0] = (short)f2bf(a0.x); af[1] = (short)f2bf(a0.y);
    af[2] = (short)f2bf(a0.z); af[3] = (short)f2bf(a0.w);
    af[4] = (short)f2bf(a1.x); af[5] = (short)f2bf(a1.y);
    af[6] = (short)f2bf(a1.z); af[7] = (short)f2bf(a1.w);
#pragma unroll
    for (int ct = 0; ct < 8; ++ct) {
      const bf16x8 bf = *(const bf16x8*)&Wt[(size_t)(ct * 16 + n15) * DD + k0];
      acc[ct] = __builtin_amdgcn_mfma_f32_16x16x32_bf16(af, bf, acc[ct], 0, 0, 0);
    }
  }

#pragma unroll
  for (int i = 0; i < 4; ++i) {
    const int r = rbase + quad * 4 + i;
    const int rr = (r < NN) ? r : NN - 1;
    const float dv = dinv[rr];
    float v[8];
    float m = 0.f;
#pragma unroll
    for (int ct = 0; ct < 8; ++ct) {
      v[ct] = acc[ct][i] * dv;
      m = fmaxf(m, fabsf(v[ct]));
    }
    // row max across the 16-lane column group (all lanes execute)
#pragma unroll
    for (int off = 1; off < 16; off <<= 1)
      m = fmaxf(m, __shfl_xor(m, off, 64));
    const float inv = (m > 0.f) ? 127.0f / m : 0.f;
    if (r < NN) {
#pragma unroll
      for (int ct = 0; ct < 8; ++ct) {
        const int q = __float2int_rn(v[ct] * inv);
        hs8[(size_t)r * DD + ct * 16 + n15] = (unsigned char)(q & 0xff);
      }
      if (n15 == 0) scalev[r] = m * (1.0f / 127.0f);
    }
  }
}

// --- SpMM over int8 hsb + row scales: dual accumulator pairs, 8-edge unroll.
//     mode 0: hout = bf16(relu(...)), partials for BN stats.
//     mode 1: out = ((x + BN1(h1)) + BN2(h2)) + relu(...)  (full JK sum) ---
__global__ __launch_bounds__(256)
void k_spmm(const unsigned char* __restrict__ hs8,
            const float* __restrict__ scalev, const int* __restrict__ rowptr,
            const int* __restrict__ col, const float* __restrict__ dinv,
            const float* __restrict__ bias, unsigned short* __restrict__ hout,
            float* __restrict__ partials, const float* __restrict__ x,
            const unsigned short* __restrict__ h1b,
            const unsigned short* __restrict__ h2b,
            const float* __restrict__ ss, float* __restrict__ out,
            const int mode) {
  const int lane = threadIdx.x & 15;     // 16 lanes / row
  const int g = threadIdx.x >> 4;        // 0..15 rows / block
  const int c8 = lane * 8;               // channel (and byte) offset
  const int d = blockIdx.x * 16 + g;
  float4 a0 = make_float4(0.f, 0.f, 0.f, 0.f);
  float4 a1 = make_float4(0.f, 0.f, 0.f, 0.f);
  float4 c0 = a0, c1 = a0;               // second accumulator pair
  float4 bs0 = a0, bs1 = a0, q0 = a0, q1 = a0;
  if (d < NN) {
    acci8(*(const uint2*)&hs8[(size_t)d * DD + c8], scalev[d], a0, a1); // self
    int j = rowptr[d];
    const int e1 = rowptr[d + 1];
    for (; j + 7 < e1; j += 8) {
      const int s0 = col[j],     s1 = col[j + 1], s2 = col[j + 2], s3 = col[j + 3];
      const int s4 = col[j + 4], s5 = col[j + 5], s6 = col[j + 6], s7 = col[j + 7];
      const uint2 u0 = *(const uint2*)&hs8[(size_t)s0 * DD + c8];
      const uint2 u1 = *(const uint2*)&hs8[(size_t)s1 * DD + c8];
      const uint2 u2 = *(const uint2*)&hs8[(size_t)s2 * DD + c8];
      const uint2 u3 = *(const uint2*)&hs8[(size_t)s3 * DD + c8];
      const uint2 u4 = *(const uint2*)&hs8[(size_t)s4 * DD + c8];
      const uint2 u5 = *(const uint2*)&hs8[(size_t)s5 * DD + c8];
      const uint2 u6 = *(const uint2*)&hs8[(size_t)s6 * DD + c8];
      const uint2 u7 = *(const uint2*)&hs8[(size_t)s7 * DD + c8];
      const float f0 = scalev[s0], f1 = scalev[s1], f2 = scalev[s2], f3 = scalev[s3];
      const float f4 = scalev[s4], f5 = scalev[s5], f6 = scalev[s6], f7 = scalev[s7];
      acci8(u0, f0, a0, a1); acci8(u1, f1, c0, c1);
      acci8(u2, f2, a0, a1); acci8(u3, f3, c0, c1);
      acci8(u4, f4, a0, a1); acci8(u5, f5, c0, c1);
      acci8(u6, f6, a0, a1); acci8(u7, f7, c0, c1);
    }
    for (; j + 3 < e1; j += 4) {
      const int s0 = col[j], s1 = col[j + 1], s2 = col[j + 2], s3 = col[j + 3];
      const uint2 u0 = *(const uint2*)&hs8[(size_t)s0 * DD + c8];
      const uint2 u1 = *(const uint2*)&hs8[(size_t)s1 * DD + c8];
      const uint2 u2 = *(const uint2*)&hs8[(size_t)s2 * DD + c8];
      const uint2 u3 = *(const uint2*)&hs8[(size_t)s3 * DD + c8];
      const float f0 = scalev[s0], f1 = scalev[s1], f2 = scalev[s2], f3 = scalev[s3];
      acci8(u0, f0, a0, a1); acci8(u1, f1, c0, c1);
      acci8(u2, f2, a0, a1); acci8(u3, f3, c0, c1);
    }
    for (; j < e1; ++j) {
      const int s0 = col[j];
      acci8(*(const uint2*)&hs8[(size_t)s0 * DD + c8], scalev[s0], a0, a1);
    }
    a0.x += c0.x; a0.y += c0.y; a0.z += c0.z; a0.w += c0.w;
    a1.x += c1.x; a1.y += c1.y; a1.z += c1.z; a1.w += c1.w;
    const float dv = dinv[d];
    const float4 bb0 = *(const float4*)&bias[c8];
    const float4 bb1 = *(const float4*)&bias[c8 + 4];
    float4 o0, o1;
    o0.x = fmaxf(fmaf(a0.x, dv, bb0.x), 0.f);
    o0.y = fmaxf(fmaf(a0.y, dv, bb0.y), 0.f);
    o0.z = fmaxf(fmaf(a0.z, dv, bb0.z), 0.f);
    o0.w = fmaxf(fmaf(a0.w, dv, bb0.w), 0.f);
    o1.x = fmaxf(fmaf(a1.x, dv, bb1.x), 0.f);
    o1.y = fmaxf(fmaf(a1.y, dv, bb1.y), 0.f);
    o1.z = fmaxf(fmaf(a1.z, dv, bb1.z), 0.f);
    o1.w = fmaxf(fmaf(a1.w, dv, bb1.w), 0.f);
    if (mode == 0) {
      uint4 pk;
      pk.x = pack2(o0.x, o0.y); pk.y = pack2(o0.z, o0.w);
      pk.z = pack2(o1.x, o1.y); pk.w = pack2(o1.z, o1.w);
      *(uint4*)&hout[(size_t)d * DD + c8] = pk;       // bf16 h for next gemm
      bs0 = o0; bs1 = o1;
      q0.x = o0.x * o0.x; q0.y = o0.y * o0.y;
      q0.z = o0.z * o0.z; q0.w = o0.w * o0.w;
      q1.x = o1.x * o1.x; q1.y = o1.y * o1.y;
      q1.z = o1.z * o1.z; q1.w = o1.w * o1.w;
    } else {
      // full JK sum: ((x + BN1(h1)) + BN2(h2)) + h3, same order as R10/R11
      float4 v0 = *(const float4*)&x[(size_t)d * DD + c8];
      float4 v1 = *(const float4*)&x[(size_t)d * DD + c8 + 4];
      const uint4 uh1 = *(const uint4*)&h1b[(size_t)d * DD + c8];
      const uint4 uh2 = *(const uint4*)&h2b[(size_t)d * DD + c8];
      {
        const float4 sc0 = *(const float4*)&ss[c8];
        const float4 sc1 = *(const float4*)&ss[c8 + 4];
        const float4 sh0 = *(const float4*)&ss[128 + c8];
        const float4 sh1 = *(const float4*)&ss[128 + c8 + 4];
        v0.x += fmaf(bflo(uh1.x), sc0.x, sh0.x);
        v0.y += fmaf(bfhi(uh1.x), sc0.y, sh0.y);
        v0.z += fmaf(bflo(uh1.y), sc0.z, sh0.z);
        v0.w += fmaf(bfhi(uh1.y), sc0.w, sh0.w);
        v1.x += fmaf(bflo(uh1.z), sc1.x, sh1.x);
        v1.y += fmaf(bfhi(uh1.z), sc1.y, sh1.y);
        v1.z += fmaf(bflo(uh1.w), sc1.z, sh1.z);
        v1.w += fmaf(bfhi(uh1.w), sc1.w, sh1.w);
      }
      {
        const float4 sc0 = *(const float4*)&ss[256 + c8];
        const float4 sc1 = *(const float4*)&ss[256 + c8 + 4];
        const float4 sh0 = *(const float4*)&ss[384 + c8];
        const float4 sh1 = *(const float4*)&ss[384 + c8 + 4];
        v0.x += fmaf(bflo(uh2.x), sc0.x, sh0.x);
        v0.y += fmaf(bfhi(uh2.x), sc0.y, sh0.y);
        v0.z += fmaf(bflo(uh2.y), sc0.z, sh0.z);
        v0.w += fmaf(bfhi(uh2.y), sc0.w, sh0.w);
        v1.x += fmaf(bflo(uh2.z), sc1.x, sh1.x);
        v1.y += fmaf(bfhi(uh2.z), sc1.y, sh1.y);
        v1.z += fmaf(bflo(uh2.w), sc1.z, sh1.z);
        v1.w += fmaf(bfhi(uh2.w), sc1.w, sh1.w);
      }
      v0.x += o0.x; v0.y += o0.y; v0.z += o0.z; v0.w += o0.w;
      v1.x += o1.x; v1.y += o1.y; v1.z += o1.z; v1.w += o1.w;
      *(float4*)&out[(size_t)d * DD + c8] = v0;
      *(float4*)&out[(size_t)d * DD + c8 + 4] = v1;
    }
  }
  if (mode == 0) {
    __shared__ float red[256 * 16];
    float* my = &red[threadIdx.x * 16];
    my[0] = bs0.x; my[1] = bs0.y; my[2] = bs0.z; my[3] = bs0.w;
    my[4] = bs1.x; my[5] = bs1.y; my[6] = bs1.z; my[7] = bs1.w;
    my[8] = q0.x;  my[9] = q0.y;  my[10] = q0.z; my[11] = q0.w;
    my[12] = q1.x; my[13] = q1.y; my[14] = q1.z; my[15] = q1.w;
    __syncthreads();
    const int t = threadIdx.x;
    float s = 0.f;
#pragma unroll
    for (int gg = 0; gg < 16; ++gg) s += red[gg * 256 + t];
    partials[(size_t)blockIdx.x * 256 + t] = s;   // coalesced
  }
}

__global__ __launch_bounds__(256)
void k_bnred(const float* __restrict__ partials, float* __restrict__ stat) {
  __shared__ float s[256];
  const int slot = blockIdx.x;
  float v = 0.f;
  for (int i = threadIdx.x; i < SPMM_GRID; i += 256)
    v += partials[(size_t)i * 256 + slot];
  s[threadIdx.x] = v;
  __syncthreads();
  for (int off = 128; off; off >>= 1) {
    if (threadIdx.x < off) s[threadIdx.x] += s[threadIdx.x + off];
    __syncthreads();
  }
  if (threadIdx.x == 0) stat[slot] = s[0];
}

__global__ __launch_bounds__(256)
void k_bnfin(const float* __restrict__ stat, float* __restrict__ ss,
             const float* __restrict__ gamma, const float* __restrict__ beta) {
  __shared__ float tot[256];            // [kind*128 + c]
  const int t = threadIdx.x;
  const float s = stat[t];
  const int lane16 = t >> 4, q = t & 15;
  const int c = lane16 * 8 + (q & 7), kind = q >> 3;
  tot[kind * 128 + c] = s;
  __syncthreads();
  if (t < 128) {
    const float m = tot[t] * (1.0f / NN);
    const float var = tot[128 + t] * (1.0f / NN) - m * m;
    const float rs = rsqrtf(var + BN_EPS);
    const float sc = rs * gamma[t];
    ss[t] = sc;
    ss[128 + t] = beta[t] - m * sc;
  }
}

extern "C" void kernel_launch(void* const* d_in, const int* in_sizes, int n_in,
                              void* d_out, int out_size, void* d_ws, size_t ws_size,
                              hipStream_t stream) {
  const float* x = (const float*)d_in[0];
  const int* ei = (const int*)d_in[1];
  const float* W = (const float*)d_in[2];
  const float* b = (const float*)d_in[3];
  const float* gamma = (const float*)d_in[4];
  const float* beta = (const float*)d_in[5];
  float* out = (float*)d_out;
  const int* srcv = ei;
  const int* dstv = ei + EE;

  char* w = (char*)d_ws;
  int* rowptr = (int*)w;     w += (size_t)NPAD * 4;
  float* dinv = (float*)w;   w += (size_t)NPAD * 4;
  float* scalev = (float*)w; w += (size_t)NPAD * 4;
  int* cntT = (int*)w;       w += (size_t)NBK * CSTRIDE * 4;
  int* baseT = (int*)w;      w += (size_t)NBK * CSTRIDE * 4;
  int* gtot = (int*)w;       w += 256 * 4;
  int* bktbase = (int*)w;    w += 260 * 4;
  int* col = (int*)w;        w += (size_t)EE * 4;
  float* ss = (float*)w;     w += 512 * 4;        // [l][scale|shift] x2 layers
  float* stat = (float*)w;   w += 256 * 4;
  unsigned short* Wt = (unsigned short*)w; w += (size_t)3 * DD * DD * 2;
  // ebuf (CSR-build only) aliases partials (spmm/bnred only); both 6.4 MB
  unsigned* ebuf = (unsigned*)w;
  float* partials = (float*)w; w += (size_t)EE * 4;
  unsigned short* h1b = (unsigned short*)w; w += (size_t)NN * DD * 2;  // h1 (bf16)
  unsigned short* h2b = (unsigned short*)w; w += (size_t)NN * DD * 2;  // h2 (bf16)
  unsigned char* hs8 = (unsigned char*)w;                              // hs (int8)

  k_cnt<<<PART_GRID, 256, 0, stream>>>(dstv, cntT);
  k_colscan<<<NBK, 64, 0, stream>>>(cntT, baseT, gtot);
  k_bktscan<<<1, 64, 0, stream>>>(gtot, bktbase);
  k_part2<<<PART_GRID, 256, 0, stream>>>(srcv, dstv, baseT, bktbase, ebuf);
  k_csr2<<<NBK, 256, 0, stream>>>(ebuf, bktbase, rowptr, col, dinv);
  k_wt<<<3, 256, 0, stream>>>(W, Wt);

  // l=0: A = x (fp32), no BN
  k_gemm<<<GEMM_GRID, 256, 0, stream>>>(x, nullptr, Wt, dinv, hs8, scalev,
                                        nullptr);
  k_spmm<<<SPMM_GRID, 256, 0, stream>>>(hs8, scalev, rowptr, col, dinv, b,
                                        h1b, partials,
                                        nullptr, nullptr, nullptr, nullptr,
                                        nullptr, 0);
  k_bnred<<<256, 256, 0, stream>>>(partials, stat);
  k_bnfin<<<1, 256, 0, stream>>>(stat, ss, gamma, beta);

  // l=1: A = BN1(h1) fused (bf16)
  k_gemm<<<GEMM_GRID, 256, 0, stream>>>(nullptr, h1b, Wt + (size_t)DD * DD,
                                        dinv, hs8, scalev, ss);
  k_spmm<<<SPMM_GRID, 256, 0, stream>>>(hs8, scalev, rowptr, col, dinv, b + DD,
                                        h2b, partials,
                                        nullptr, nullptr, nullptr, nullptr,
                                        nullptr, 0);
  k_bnred<<<256, 256, 0, stream>>>(partials, stat);
  k_bnfin<<<1, 256, 0, stream>>>(stat, ss + 256, gamma + DD, beta + DD);

  // l=2: A = BN2(h2) fused (bf16); final spmm does the whole JK sum
  k_gemm<<<GEMM_GRID, 256, 0, stream>>>(nullptr, h2b, Wt + (size_t)2 * DD * DD,
                                        dinv, hs8, scalev, ss + 256);
  k_spmm<<<SPMM_GRID, 256, 0, stream>>>(hs8, scalev, rowptr, col, dinv,
                                        b + 2 * DD, nullptr, nullptr,
                                        x, h1b, h2b, ss, out, 1);
}

// Round 9
// 452.138 us; speedup vs baseline: 1.6493x; 1.1080x over previous
//
#include <hip/hip_runtime.h>
#include <hip/hip_bf16.h>

// GCN (3-layer, JK=sum) on MI355X.
// R14: (a) k_bnred was a 1KB-stride read (each 64B partials line fetched by
//      ~8 XCDs -> ~50MB/launch, ~20us); now two-phase coalesced: 250 blocks
//      x 25 consecutive rows -> stat2[250][256], bnfin sums 250 coalesced
//      rows. (b) k_bktscan launch removed: part2/csr2 recompute the
//      196-entry bucket scan from gtot per block (196 loads, trivial).
//      Numerics identical to R13 (absmax 0.244).
// R13: hsb int8 + per-row scale (gather granule 128B, 8x better error than
//      fp8 e4m3 which failed at 0.81). R11: JK-sum deferred to final spmm.
// R10: inter-layer h bf16; spmm dual-acc 8-edge unroll. R9: BN affine fused
//      into gemm A-path. R8: LDS radix partition CSR build. R7: MFMA gemm.

constexpr int NN = 100000;
constexpr int EE = 1600000;
constexpr int DD = 128;
constexpr float BN_EPS = 1e-5f;
constexpr int NPAD = 100096;
constexpr int SPMM_GRID = NN / 16;              // 6250
constexpr int GEMM_GRID = (NN + 63) / 64;       // 1563
constexpr int BNRED_GRID = 250;                 // 6250/25 rows each

// radix partition params
constexpr int NBK = (NN + 511) / 512;           // 196 coarse buckets (dst>>9)
constexpr int PB = 4096;                        // edges per partition block
constexpr int PART_GRID = (EE + PB - 1) / PB;   // 391
constexpr int CSTRIDE = 400;                    // >= PART_GRID, count-table stride
constexpr int CAPL = 10240;                     // LDS colseg capacity

typedef __attribute__((ext_vector_type(8))) short bf16x8;
typedef __attribute__((ext_vector_type(4))) float f32x4;

__device__ __forceinline__ float bfhi(unsigned int u) {
  union { unsigned int i; float f; } v; v.i = u & 0xffff0000u; return v.f;
}
__device__ __forceinline__ float bflo(unsigned int u) {
  union { unsigned int i; float f; } v; v.i = u << 16; return v.f;
}
__device__ __forceinline__ unsigned short f2bf(float f) {
  union { float f; unsigned int i; } v;
  v.f = f;
  unsigned int r = v.i + 0x7FFFu + ((v.i >> 16) & 1u);   // RNE
  return (unsigned short)(r >> 16);
}
__device__ __forceinline__ unsigned pack2(float lo, float hi) {
  return (unsigned)f2bf(lo) | ((unsigned)f2bf(hi) << 16);
}
// int8 row-scaled decode: 8 channels from one uint2, scale sc
__device__ __forceinline__ void acci8(uint2 u, float sc, float4& a0, float4& a1) {
  a0.x += sc * (float)(int)(signed char)(u.x & 0xffu);
  a0.y += sc * (float)(int)(signed char)((u.x >> 8) & 0xffu);
  a0.z += sc * (float)(int)(signed char)((u.x >> 16) & 0xffu);
  a0.w += sc * (float)(int)(signed char)(u.x >> 24);
  a1.x += sc * (float)(int)(signed char)(u.y & 0xffu);
  a1.y += sc * (float)(int)(signed char)((u.y >> 8) & 0xffu);
  a1.z += sc * (float)(int)(signed char)((u.y >> 16) & 0xffu);
  a1.w += sc * (float)(int)(signed char)(u.y >> 24);
}
__device__ __forceinline__ int wave_incl_scan(int v, int lane) {
#pragma unroll
  for (int off = 1; off < 64; off <<= 1) {
    int x = __shfl_up(v, off, 64);
    if (lane >= off) v += x;
  }
  return v;
}

// --- CSR build pass 1: per-(block,bucket) counts, transposed [bkt][blk] ---
__global__ __launch_bounds__(256)
void k_cnt(const int* __restrict__ dst, int* __restrict__ cntT) {
  __shared__ int cnt[256];
  const int t = threadIdx.x;
  const int e0 = blockIdx.x * PB;
  const int nv = min(PB, EE - e0);
  cnt[t] = 0;
  __syncthreads();
  for (int i = t; i < nv; i += 256)
    atomicAdd(&cnt[dst[e0 + i] >> 9], 1);
  __syncthreads();
  if (t < NBK) cntT[t * CSTRIDE + blockIdx.x] = cnt[t];
}

// --- per-bucket column scan over blocks; gtot[bkt] = total edges of bkt ---
__global__ __launch_bounds__(64)
void k_colscan(const int* __restrict__ cntT, int* __restrict__ baseT,
               int* __restrict__ gtot) {
  const int b = blockIdx.x;
  const int lane = threadIdx.x;
  int c[7];
  int ls = 0;
#pragma unroll
  for (int j = 0; j < 7; ++j) {
    const int idx = lane * 7 + j;
    c[j] = (idx < PART_GRID) ? cntT[b * CSTRIDE + idx] : 0;
    ls += c[j];
  }
  const int is = wave_incl_scan(ls, lane);
  int run = is - ls;
#pragma unroll
  for (int j = 0; j < 7; ++j) {
    const int idx = lane * 7 + j;
    if (idx < PART_GRID) baseT[b * CSTRIDE + idx] = run;
    run += c[j];
  }
  if (lane == 63) gtot[b] = is;
}

// --- CSR build pass 2: LDS counting sort per block, coalesced ebuf writes.
//     Bucket-base scan recomputed per block from gtot (replaces k_bktscan) ---
__global__ __launch_bounds__(256)
void k_part2(const int* __restrict__ src, const int* __restrict__ dst,
             const int* __restrict__ baseT, const int* __restrict__ gtot,
             unsigned* __restrict__ ebuf) {
  __shared__ unsigned sorted[PB];
  __shared__ unsigned char sortedb[PB];
  alignas(16) __shared__ int cnt[256];
  __shared__ int cur[256], start[256], gbase[256];
  __shared__ int bktb[200];
  const int t = threadIdx.x;
  const int lane = t & 63;
  const int e0 = blockIdx.x * PB;
  const int nv = min(PB, EE - e0);
  cnt[t] = 0;
  if (t < 64) {   // recompute exclusive bucket-base scan from gtot
    int c[4];
    int ls = 0;
#pragma unroll
    for (int j = 0; j < 4; ++j) {
      const int idx = t * 4 + j;
      c[j] = (idx < NBK) ? gtot[idx] : 0;
      ls += c[j];
    }
    const int is = wave_incl_scan(ls, t);
    int run = is - ls;
#pragma unroll
    for (int j = 0; j < 4; ++j) {
      const int idx = t * 4 + j;
      if (idx < NBK) bktb[idx] = run;
      run += c[j];
    }
  }
  __syncthreads();
  if (t < NBK) gbase[t] = bktb[t] + baseT[t * CSTRIDE + blockIdx.x];
  int es[PB / 256], ed[PB / 256];
#pragma unroll
  for (int j = 0; j < PB / 256; ++j) {
    const int i = t + j * 256;
    if (i < nv) {
      es[j] = src[e0 + i];
      ed[j] = dst[e0 + i];
      atomicAdd(&cnt[ed[j] >> 9], 1);
    } else {
      ed[j] = -1;
    }
  }
  __syncthreads();
  if (t < 64) {
    const int4 c = *(const int4*)&cnt[lane * 4];
    const int ls = c.x + c.y + c.z + c.w;
    const int is = wave_incl_scan(ls, lane);
    int run = is - ls;
    start[lane * 4] = run; cur[lane * 4] = run; run += c.x;
    start[lane * 4 + 1] = run; cur[lane * 4 + 1] = run; run += c.y;
    start[lane * 4 + 2] = run; cur[lane * 4 + 2] = run; run += c.z;
    start[lane * 4 + 3] = run; cur[lane * 4 + 3] = run;
  }
  __syncthreads();
#pragma unroll
  for (int j = 0; j < PB / 256; ++j) {
    if (ed[j] >= 0) {
      const int bkt = ed[j] >> 9;
      const int p = atomicAdd(&cur[bkt], 1);
      sorted[p] = ((unsigned)es[j] << 9) | (unsigned)(ed[j] & 511);
      sortedb[p] = (unsigned char)bkt;
    }
  }
  __syncthreads();
  for (int i = t; i < nv; i += 256) {
    const int bkt = sortedb[i];
    ebuf[(size_t)gbase[bkt] + (i - start[bkt])] = sorted[i];
  }
}

// --- CSR finish: one block per bucket, all writes coalesced.
//     Bucket bases recomputed from gtot (replaces k_bktscan). ---
__global__ __launch_bounds__(256)
void k_csr2(const unsigned* __restrict__ ebuf, const int* __restrict__ gtot,
            int* __restrict__ rowptr, int* __restrict__ col,
            float* __restrict__ dinv) {
  __shared__ int rowcnt[512], rowbase[512], rowcur[512];
  __shared__ int bktb[200];
  __shared__ unsigned colseg[CAPL];
  const int b = blockIdx.x;
  const int t = threadIdx.x;
  if (t < 64) {   // recompute exclusive bucket-base scan (+ total at [NBK])
    int c[4];
    int ls = 0;
#pragma unroll
    for (int j = 0; j < 4; ++j) {
      const int idx = t * 4 + j;
      c[j] = (idx < NBK) ? gtot[idx] : 0;
      ls += c[j];
    }
    const int is = wave_incl_scan(ls, t);
    int run = is - ls;
#pragma unroll
    for (int j = 0; j < 4; ++j) {
      const int idx = t * 4 + j;
      if (idx < NBK) bktb[idx] = run;
      run += c[j];
    }
    if (t == 63) bktb[NBK] = is;
  }
  rowcnt[t] = 0;
  rowcnt[t + 256] = 0;
  __syncthreads();
  const int ebase = bktb[b];
  const int n = min(bktb[b + 1] - ebase, CAPL);
  const unsigned* eb = &ebuf[ebase];
  for (int i = t; i < n; i += 256)
    atomicAdd(&rowcnt[eb[i] & 511u], 1);
  __syncthreads();
  if (t < 64) {
    int v[8];
    int ls = 0;
#pragma unroll
    for (int j = 0; j < 8; ++j) { v[j] = rowcnt[t * 8 + j]; ls += v[j]; }
    const int is = wave_incl_scan(ls, t);
    int run = is - ls;
#pragma unroll
    for (int j = 0; j < 8; ++j) {
      rowbase[t * 8 + j] = run;
      rowcur[t * 8 + j] = run;
      run += v[j];
    }
  }
  __syncthreads();
#pragma unroll
  for (int h = 0; h < 2; ++h) {
    const int rl = t + h * 256;
    const int r = b * 512 + rl;
    if (r < NN) {
      rowptr[r] = ebase + rowbase[rl];
      dinv[r] = rsqrtf((float)rowcnt[rl] + 1.0f);
    }
  }
  if (b == NBK - 1 && t == 0) rowptr[NN] = ebase + n;
  for (int i = t; i < n; i += 256) {
    const unsigned u = eb[i];
    const int p = atomicAdd(&rowcur[u & 511u], 1);
    colseg[p] = u >> 9;
  }
  __syncthreads();
  for (int i = t; i < n; i += 256) col[ebase + i] = (int)colseg[i];
}

// --- W transpose+cvt: Wt[l][c][k] = bf16(W[l][k][c]) --- grid = 3 blocks
__global__ __launch_bounds__(256)
void k_wt(const float* __restrict__ W, unsigned short* __restrict__ Wt) {
  const float* Ws = W + (size_t)blockIdx.x * DD * DD;
  unsigned short* Wo = Wt + (size_t)blockIdx.x * DD * DD;
  for (int i = threadIdx.x; i < DD * DD; i += 256) {
    const int k = i >> 7, c = i & 127;
    Wo[c * DD + k] = f2bf(Ws[i]);
  }
}

// --- MFMA GEMM with optional fused BN affine on A; int8+row-scale output ---
__global__ __launch_bounds__(256)
void k_gemm(const float* __restrict__ hf, const unsigned short* __restrict__ hb,
            const unsigned short* __restrict__ Wt,
            const float* __restrict__ dinv, unsigned char* __restrict__ hs8,
            float* __restrict__ scalev, const float* __restrict__ ss) {
  const int lane = threadIdx.x & 63;
  const int wave = threadIdx.x >> 6;          // 0..3
  const int n15 = lane & 15;
  const int quad = lane >> 4;                 // 0..3
  const int rbase = blockIdx.x * 64 + wave * 16;
  const int r0 = rbase + n15;
  const int arow = (r0 < NN) ? r0 : NN - 1;   // clamped load row

  f32x4 acc[8];
#pragma unroll
  for (int ct = 0; ct < 8; ++ct) acc[ct] = (f32x4){0.f, 0.f, 0.f, 0.f};

#pragma unroll
  for (int kc = 0; kc < 4; ++kc) {
    const int k0 = kc * 32 + quad * 8;
    float4 a0, a1;
    if (hb) {   // bf16 h (one 16B load covers all 8 elems)
      const uint4 u = *(const uint4*)&hb[(size_t)arow * DD + k0];
      a0.x = bflo(u.x); a0.y = bfhi(u.x);
      a0.z = bflo(u.y); a0.w = bfhi(u.y);
      a1.x = bflo(u.z); a1.y = bfhi(u.z);
      a1.z = bflo(u.w); a1.w = bfhi(u.w);
    } else {
      a0 = *(const float4*)&hf[(size_t)arow * DD + k0];
      a1 = *(const float4*)&hf[(size_t)arow * DD + k0 + 4];
    }
    if (ss) {  // fused BatchNorm affine
      const float4 sc0 = *(const float4*)&ss[k0];
      const float4 sc1 = *(const float4*)&ss[k0 + 4];
      const float4 sh0 = *(const float4*)&ss[128 + k0];
      const float4 sh1 = *(const float4*)&ss[128 + k0 + 4];
      a0.x = fmaf(a0.x, sc0.x, sh0.x); a0.y = fmaf(a0.y, sc0.y, sh0.y);
      a0.z = fmaf(a0.z, sc0.z, sh0.z); a0.w = fmaf(a0.w, sc0.w, sh0.w);
      a1.x = fmaf(a1.x, sc1.x, sh1.x); a1.y = fmaf(a1.y, sc1.y, sh1.y);
      a1.z = fmaf(a1.z, sc1.z, sh1.z); a1.w = fmaf(a1.w, sc1.w, sh1.w);
    }
    bf16x8 af;
    af[0] = (short)f2bf(a0.x); af[1] = (short)f2bf(a0.y);
    af[2] = (short)f2bf(a0.z); af[3] = (short)f2bf(a0.w);
    af[4] = (short)f2bf(a1.x); af[5] = (short)f2bf(a1.y);
    af[6] = (short)f2bf(a1.z); af[7] = (short)f2bf(a1.w);
#pragma unroll
    for (int ct = 0; ct < 8; ++ct) {
      const bf16x8 bf = *(const bf16x8*)&Wt[(size_t)(ct * 16 + n15) * DD + k0];
      acc[ct] = __builtin_amdgcn_mfma_f32_16x16x32_bf16(af, bf, acc[ct], 0, 0, 0);
    }
  }

#pragma unroll
  for (int i = 0; i < 4; ++i) {
    const int r = rbase + quad * 4 + i;
    const int rr = (r < NN) ? r : NN - 1;
    const float dv = dinv[rr];
    float v[8];
    float m = 0.f;
#pragma unroll
    for (int ct = 0; ct < 8; ++ct) {
      v[ct] = acc[ct][i] * dv;
      m = fmaxf(m, fabsf(v[ct]));
    }
    // row max across the 16-lane column group (all lanes execute)
#pragma unroll
    for (int off = 1; off < 16; off <<= 1)
      m = fmaxf(m, __shfl_xor(m, off, 64));
    const float inv = (m > 0.f) ? 127.0f / m : 0.f;
    if (r < NN) {
#pragma unroll
      for (int ct = 0; ct < 8; ++ct) {
        const int q = __float2int_rn(v[ct] * inv);
        hs8[(size_t)r * DD + ct * 16 + n15] = (unsigned char)(q & 0xff);
      }
      if (n15 == 0) scalev[r] = m * (1.0f / 127.0f);
    }
  }
}

// --- SpMM over int8 hsb + row scales: dual accumulator pairs, 8-edge unroll.
//     mode 0: hout = bf16(relu(...)), partials for BN stats.
//     mode 1: out = ((x + BN1(h1)) + BN2(h2)) + relu(...)  (full JK sum) ---
__global__ __launch_bounds__(256)
void k_spmm(const unsigned char* __restrict__ hs8,
            const float* __restrict__ scalev, const int* __restrict__ rowptr,
            const int* __restrict__ col, const float* __restrict__ dinv,
            const float* __restrict__ bias, unsigned short* __restrict__ hout,
            float* __restrict__ partials, const float* __restrict__ x,
            const unsigned short* __restrict__ h1b,
            const unsigned short* __restrict__ h2b,
            const float* __restrict__ ss, float* __restrict__ out,
            const int mode) {
  const int lane = threadIdx.x & 15;     // 16 lanes / row
  const int g = threadIdx.x >> 4;        // 0..15 rows / block
  const int c8 = lane * 8;               // channel (and byte) offset
  const int d = blockIdx.x * 16 + g;
  float4 a0 = make_float4(0.f, 0.f, 0.f, 0.f);
  float4 a1 = make_float4(0.f, 0.f, 0.f, 0.f);
  float4 c0 = a0, c1 = a0;               // second accumulator pair
  float4 bs0 = a0, bs1 = a0, q0 = a0, q1 = a0;
  if (d < NN) {
    acci8(*(const uint2*)&hs8[(size_t)d * DD + c8], scalev[d], a0, a1); // self
    int j = rowptr[d];
    const int e1 = rowptr[d + 1];
    for (; j + 7 < e1; j += 8) {
      const int s0 = col[j],     s1 = col[j + 1], s2 = col[j + 2], s3 = col[j + 3];
      const int s4 = col[j + 4], s5 = col[j + 5], s6 = col[j + 6], s7 = col[j + 7];
      const uint2 u0 = *(const uint2*)&hs8[(size_t)s0 * DD + c8];
      const uint2 u1 = *(const uint2*)&hs8[(size_t)s1 * DD + c8];
      const uint2 u2 = *(const uint2*)&hs8[(size_t)s2 * DD + c8];
      const uint2 u3 = *(const uint2*)&hs8[(size_t)s3 * DD + c8];
      const uint2 u4 = *(const uint2*)&hs8[(size_t)s4 * DD + c8];
      const uint2 u5 = *(const uint2*)&hs8[(size_t)s5 * DD + c8];
      const uint2 u6 = *(const uint2*)&hs8[(size_t)s6 * DD + c8];
      const uint2 u7 = *(const uint2*)&hs8[(size_t)s7 * DD + c8];
      const float f0 = scalev[s0], f1 = scalev[s1], f2 = scalev[s2], f3 = scalev[s3];
      const float f4 = scalev[s4], f5 = scalev[s5], f6 = scalev[s6], f7 = scalev[s7];
      acci8(u0, f0, a0, a1); acci8(u1, f1, c0, c1);
      acci8(u2, f2, a0, a1); acci8(u3, f3, c0, c1);
      acci8(u4, f4, a0, a1); acci8(u5, f5, c0, c1);
      acci8(u6, f6, a0, a1); acci8(u7, f7, c0, c1);
    }
    for (; j + 3 < e1; j += 4) {
      const int s0 = col[j], s1 = col[j + 1], s2 = col[j + 2], s3 = col[j + 3];
      const uint2 u0 = *(const uint2*)&hs8[(size_t)s0 * DD + c8];
      const uint2 u1 = *(const uint2*)&hs8[(size_t)s1 * DD + c8];
      const uint2 u2 = *(const uint2*)&hs8[(size_t)s2 * DD + c8];
      const uint2 u3 = *(const uint2*)&hs8[(size_t)s3 * DD + c8];
      const float f0 = scalev[s0], f1 = scalev[s1], f2 = scalev[s2], f3 = scalev[s3];
      acci8(u0, f0, a0, a1); acci8(u1, f1, c0, c1);
      acci8(u2, f2, a0, a1); acci8(u3, f3, c0, c1);
    }
    for (; j < e1; ++j) {
      const int s0 = col[j];
      acci8(*(const uint2*)&hs8[(size_t)s0 * DD + c8], scalev[s0], a0, a1);
    }
    a0.x += c0.x; a0.y += c0.y; a0.z += c0.z; a0.w += c0.w;
    a1.x += c1.x; a1.y += c1.y; a1.z += c1.z; a1.w += c1.w;
    const float dv = dinv[d];
    const float4 bb0 = *(const float4*)&bias[c8];
    const float4 bb1 = *(const float4*)&bias[c8 + 4];
    float4 o0, o1;
    o0.x = fmaxf(fmaf(a0.x, dv, bb0.x), 0.f);
    o0.y = fmaxf(fmaf(a0.y, dv, bb0.y), 0.f);
    o0.z = fmaxf(fmaf(a0.z, dv, bb0.z), 0.f);
    o0.w = fmaxf(fmaf(a0.w, dv, bb0.w), 0.f);
    o1.x = fmaxf(fmaf(a1.x, dv, bb1.x), 0.f);
    o1.y = fmaxf(fmaf(a1.y, dv, bb1.y), 0.f);
    o1.z = fmaxf(fmaf(a1.z, dv, bb1.z), 0.f);
    o1.w = fmaxf(fmaf(a1.w, dv, bb1.w), 0.f);
    if (mode == 0) {
      uint4 pk;
      pk.x = pack2(o0.x, o0.y); pk.y = pack2(o0.z, o0.w);
      pk.z = pack2(o1.x, o1.y); pk.w = pack2(o1.z, o1.w);
      *(uint4*)&hout[(size_t)d * DD + c8] = pk;       // bf16 h for next gemm
      bs0 = o0; bs1 = o1;
      q0.x = o0.x * o0.x; q0.y = o0.y * o0.y;
      q0.z = o0.z * o0.z; q0.w = o0.w * o0.w;
      q1.x = o1.x * o1.x; q1.y = o1.y * o1.y;
      q1.z = o1.z * o1.z; q1.w = o1.w * o1.w;
    } else {
      // full JK sum: ((x + BN1(h1)) + BN2(h2)) + h3, same order as R10/R11
      float4 v0 = *(const float4*)&x[(size_t)d * DD + c8];
      float4 v1 = *(const float4*)&x[(size_t)d * DD + c8 + 4];
      const uint4 uh1 = *(const uint4*)&h1b[(size_t)d * DD + c8];
      const uint4 uh2 = *(const uint4*)&h2b[(size_t)d * DD + c8];
      {
        const float4 sc0 = *(const float4*)&ss[c8];
        const float4 sc1 = *(const float4*)&ss[c8 + 4];
        const float4 sh0 = *(const float4*)&ss[128 + c8];
        const float4 sh1 = *(const float4*)&ss[128 + c8 + 4];
        v0.x += fmaf(bflo(uh1.x), sc0.x, sh0.x);
        v0.y += fmaf(bfhi(uh1.x), sc0.y, sh0.y);
        v0.z += fmaf(bflo(uh1.y), sc0.z, sh0.z);
        v0.w += fmaf(bfhi(uh1.y), sc0.w, sh0.w);
        v1.x += fmaf(bflo(uh1.z), sc1.x, sh1.x);
        v1.y += fmaf(bfhi(uh1.z), sc1.y, sh1.y);
        v1.z += fmaf(bflo(uh1.w), sc1.z, sh1.z);
        v1.w += fmaf(bfhi(uh1.w), sc1.w, sh1.w);
      }
      {
        const float4 sc0 = *(const float4*)&ss[256 + c8];
        const float4 sc1 = *(const float4*)&ss[256 + c8 + 4];
        const float4 sh0 = *(const float4*)&ss[384 + c8];
        const float4 sh1 = *(const float4*)&ss[384 + c8 + 4];
        v0.x += fmaf(bflo(uh2.x), sc0.x, sh0.x);
        v0.y += fmaf(bfhi(uh2.x), sc0.y, sh0.y);
        v0.z += fmaf(bflo(uh2.y), sc0.z, sh0.z);
        v0.w += fmaf(bfhi(uh2.y), sc0.w, sh0.w);
        v1.x += fmaf(bflo(uh2.z), sc1.x, sh1.x);
        v1.y += fmaf(bfhi(uh2.z), sc1.y, sh1.y);
        v1.z += fmaf(bflo(uh2.w), sc1.z, sh1.z);
        v1.w += fmaf(bfhi(uh2.w), sc1.w, sh1.w);
      }
      v0.x += o0.x; v0.y += o0.y; v0.z += o0.z; v0.w += o0.w;
      v1.x += o1.x; v1.y += o1.y; v1.z += o1.z; v1.w += o1.w;
      *(float4*)&out[(size_t)d * DD + c8] = v0;
      *(float4*)&out[(size_t)d * DD + c8 + 4] = v1;
    }
  }
  if (mode == 0) {
    __shared__ float red[256 * 16];
    float* my = &red[threadIdx.x * 16];
    my[0] = bs0.x; my[1] = bs0.y; my[2] = bs0.z; my[3] = bs0.w;
    my[4] = bs1.x; my[5] = bs1.y; my[6] = bs1.z; my[7] = bs1.w;
    my[8] = q0.x;  my[9] = q0.y;  my[10] = q0.z; my[11] = q0.w;
    my[12] = q1.x; my[13] = q1.y; my[14] = q1.z; my[15] = q1.w;
    __syncthreads();
    const int t = threadIdx.x;
    float s = 0.f;
#pragma unroll
    for (int gg = 0; gg < 16; ++gg) s += red[gg * 256 + t];
    partials[(size_t)blockIdx.x * 256 + t] = s;   // coalesced
  }
}

// --- BN-stat reduction phase 1: coalesced. Block j sums 25 consecutive
//     partials rows -> stat2[j][256]. ---
__global__ __launch_bounds__(256)
void k_bnred(const float* __restrict__ partials, float* __restrict__ stat2) {
  const int t = threadIdx.x;
  const int j = blockIdx.x;              // 0..249
  float v = 0.f;
#pragma unroll 5
  for (int r = 0; r < 25; ++r)
    v += partials[(size_t)(j * 25 + r) * 256 + t];
  stat2[(size_t)j * 256 + t] = v;
}

// --- BN-stat finish: sum 250 stat2 rows (coalesced across threads), ss ---
__global__ __launch_bounds__(256)
void k_bnfin(const float* __restrict__ stat2, float* __restrict__ ss,
             const float* __restrict__ gamma, const float* __restrict__ beta) {
  __shared__ float tot[256];            // [kind*128 + c]
  const int t = threadIdx.x;
  float s = 0.f;
  for (int j = 0; j < BNRED_GRID; ++j)
    s += stat2[(size_t)j * 256 + t];
  const int lane16 = t >> 4, q = t & 15;
  const int c = lane16 * 8 + (q & 7), kind = q >> 3;
  tot[kind * 128 + c] = s;
  __syncthreads();
  if (t < 128) {
    const float m = tot[t] * (1.0f / NN);
    const float var = tot[128 + t] * (1.0f / NN) - m * m;
    const float rs = rsqrtf(var + BN_EPS);
    const float sc = rs * gamma[t];
    ss[t] = sc;
    ss[128 + t] = beta[t] - m * sc;
  }
}

extern "C" void kernel_launch(void* const* d_in, const int* in_sizes, int n_in,
                              void* d_out, int out_size, void* d_ws, size_t ws_size,
                              hipStream_t stream) {
  const float* x = (const float*)d_in[0];
  const int* ei = (const int*)d_in[1];
  const float* W = (const float*)d_in[2];
  const float* b = (const float*)d_in[3];
  const float* gamma = (const float*)d_in[4];
  const float* beta = (const float*)d_in[5];
  float* out = (float*)d_out;
  const int* srcv = ei;
  const int* dstv = ei + EE;

  char* w = (char*)d_ws;
  int* rowptr = (int*)w;     w += (size_t)NPAD * 4;
  float* dinv = (float*)w;   w += (size_t)NPAD * 4;
  float* scalev = (float*)w; w += (size_t)NPAD * 4;
  int* cntT = (int*)w;       w += (size_t)NBK * CSTRIDE * 4;
  int* baseT = (int*)w;      w += (size_t)NBK * CSTRIDE * 4;
  int* gtot = (int*)w;       w += 256 * 4;
  float* ss = (float*)w;     w += 512 * 4;        // [l][scale|shift] x2 layers
  float* stat2 = (float*)w;  w += (size_t)BNRED_GRID * 256 * 4;   // 256KB
  int* col = (int*)w;        w += (size_t)EE * 4;
  unsigned short* Wt = (unsigned short*)w; w += (size_t)3 * DD * DD * 2;
  // ebuf (CSR-build only) aliases partials (spmm/bnred only); both 6.4 MB
  unsigned* ebuf = (unsigned*)w;
  float* partials = (float*)w; w += (size_t)EE * 4;
  unsigned short* h1b = (unsigned short*)w; w += (size_t)NN * DD * 2;  // h1 (bf16)
  unsigned short* h2b = (unsigned short*)w; w += (size_t)NN * DD * 2;  // h2 (bf16)
  unsigned char* hs8 = (unsigned char*)w;                              // hs (int8)

  k_cnt<<<PART_GRID, 256, 0, stream>>>(dstv, cntT);
  k_colscan<<<NBK, 64, 0, stream>>>(cntT, baseT, gtot);
  k_part2<<<PART_GRID, 256, 0, stream>>>(srcv, dstv, baseT, gtot, ebuf);
  k_csr2<<<NBK, 256, 0, stream>>>(ebuf, gtot, rowptr, col, dinv);
  k_wt<<<3, 256, 0, stream>>>(W, Wt);

  // l=0: A = x (fp32), no BN
  k_gemm<<<GEMM_GRID, 256, 0, stream>>>(x, nullptr, Wt, dinv, hs8, scalev,
                                        nullptr);
  k_spmm<<<SPMM_GRID, 256, 0, stream>>>(hs8, scalev, rowptr, col, dinv, b,
                                        h1b, partials,
                                        nullptr, nullptr, nullptr, nullptr,
                                        nullptr, 0);
  k_bnred<<<BNRED_GRID, 256, 0, stream>>>(partials, stat2);
  k_bnfin<<<1, 256, 0, stream>>>(stat2, ss, gamma, beta);

  // l=1: A = BN1(h1) fused (bf16)
  k_gemm<<<GEMM_GRID, 256, 0, stream>>>(nullptr, h1b, Wt + (size_t)DD * DD,
                                        dinv, hs8, scalev, ss);
  k_spmm<<<SPMM_GRID, 256, 0, stream>>>(hs8, scalev, rowptr, col, dinv, b + DD,
                                        h2b, partials,
                                        nullptr, nullptr, nullptr, nullptr,
                                        nullptr, 0);
  k_bnred<<<BNRED_GRID, 256, 0, stream>>>(partials, stat2);
  k_bnfin<<<1, 256, 0, stream>>>(stat2, ss + 256, gamma + DD, beta + DD);

  // l=2: A = BN2(h2) fused (bf16); final spmm does the whole JK sum
  k_gemm<<<GEMM_GRID, 256, 0, stream>>>(nullptr, h2b, Wt + (size_t)2 * DD * DD,
                                        dinv, hs8, scalev, ss + 256);
  k_spmm<<<SPMM_GRID, 256, 0, stream>>>(hs8, scalev, rowptr, col, dinv,
                                        b + 2 * DD, nullptr, nullptr,
                                        x, h1b, h2b, ss, out, 1);
}